// Round 17
// baseline (3300.514 us; speedup 1.0000x reference)
//
#include <hip/hip_runtime.h>
#include <math.h>

#define NE 320000
#define NNODES 10000
#define EB 32
#define NBLK (NE / EB)
#define AST 360   // Ah stride (f16 elems)
#define BST 264   // AhB stride (f16 elems)
#define SST 98    // padded S/scal stride (f16)

typedef _Float16 f16x8 __attribute__((ext_vector_type(8)));
typedef float f32x4 __attribute__((ext_vector_type(4)));
typedef float f32x16 __attribute__((ext_vector_type(16)));

__device__ __forceinline__ float silu(float x) { return x / (1.0f + __expf(-x)); }
__device__ __forceinline__ float cutf(float len) {
    float x = len * (1.0f / 6.0f);
    float x2 = x * x, x6 = x2 * x2 * x2;
    float f = 1.0f - 28.0f * x6 + 48.0f * x6 * x - 21.0f * x6 * x2;
    return (x < 1.0f) ? f : 0.0f;
}

// ---------------------------------------------------------------- zero
__global__ __launch_bounds__(256) void k_zero(float* __restrict__ p, int n) {
    int i = blockIdx.x * 256 + threadIdx.x;
    if (i < n) p[i] = 0.f;
}

// ---------------------------------------------------------------- sort prep
__global__ __launch_bounds__(256) void k_hist(const int* __restrict__ eidx,
                                              int* __restrict__ cnt) {
    int e = blockIdx.x * 256 + threadIdx.x;
    if (e < NE) atomicAdd(&cnt[eidx[e]], 1);
}

__global__ __launch_bounds__(256) void k_scan(const int* __restrict__ cnt,
                                              int* __restrict__ seg,
                                              int* __restrict__ cursor) {
    __shared__ int part[256];
    __shared__ int base[256];
    int t = threadIdx.x;
    int start = t * 40;
    int s = 0;
    for (int i = 0; i < 40; ++i) {
        int idx = start + i;
        if (idx < NNODES) s += cnt[idx];
    }
    part[t] = s;
    __syncthreads();
    if (t == 0) {
        int run = 0;
        for (int i = 0; i < 256; ++i) { base[i] = run; run += part[i]; }
    }
    __syncthreads();
    int run = base[t];
    for (int i = 0; i < 40; ++i) {
        int idx = start + i;
        if (idx < NNODES) {
            int c = cnt[idx];       // read BEFORE overwriting (cnt may alias cursor)
            seg[idx] = run;
            cursor[idx] = run;
            run += c;
        }
    }
    if (t == 0) seg[NNODES] = NE;
}

__global__ __launch_bounds__(256) void k_place(const int* __restrict__ eidx,
                                               int* __restrict__ cursor,
                                               int* __restrict__ eord) {
    int e = blockIdx.x * 256 + threadIdx.x;
    if (e < NE) {
        int p = atomicAdd(&cursor[eidx[e]], 1);
        eord[p] = e;
    }
}

// ---------------------------------------------------------------- fragment-major pack for MLP weights (16x16 path)
__global__ __launch_bounds__(256) void k_packf(const float* __restrict__ src,
                                               _Float16* __restrict__ dst,
                                               int K, int KS, int NT, int stride,
                                               int colOff) {
    int i = blockIdx.x * 256 + threadIdx.x;
    if (i >= NT * KS * 512) return;
    int j = i & 7, lane = (i >> 3) & 63;
    int blk = i >> 9;
    int ks = blk % KS, nt = blk / KS;
    int k = ks * 32 + (lane >> 4) * 8 + j;
    int n = colOff + nt * 16 + (lane & 15);
    dst[i] = (k < K) ? (_Float16)src[(size_t)k * stride + n] : (_Float16)0.f;
}

// ---------------------------------------------------------------- stage-major pack of Wfinlat (32x32 pipeline, R9-proven)
__global__ __launch_bounds__(256) void k_packfin3(const float* __restrict__ W,
                                                  _Float16* __restrict__ dst) {
    int i = blockIdx.x * 256 + threadIdx.x;  // < 786432
    int j = i & 7, lane = (i >> 3) & 63, q = (i >> 9) & 15, s = i >> 13;
    int l = s >> 5, ke = s & 31;
    int c = q * 16 + (lane >> 5) * 8 + j;
    int n = l * 1024 + ke * 32 + (lane & 31);
    dst[i] = (_Float16)W[(size_t)c * 3072 + n];
}

// ---------------------------------------------------------------- 32x32x16 pack of Wro1 (readout B)
__global__ __launch_bounds__(256) void k_packro5(const float* __restrict__ W,
                                                 _Float16* __restrict__ dst) {
    int i = blockIdx.x * 256 + threadIdx.x;  // < 90112
    if (i >= 90112) return;
    int j = i & 7, lane = (i >> 3) & 63, u = i >> 9;
    int cb = u / 22, ks2 = u - cb * 22;
    int k = ks2 * 16 + (lane >> 5) * 8 + j;
    int n = cb * 32 + (lane & 31);
    dst[i] = (_Float16)W[(size_t)k * 256 + n];
}

// ---------------------------------------------------------------- MFMA GEMM, 32 edges (2 m-tiles), frag-major B
template <int NT>
__device__ __forceinline__ void mfma_gemm2(int ksteps, const _Float16* Ah, int astride,
                                           const _Float16* __restrict__ Wt, int t,
                                           f32x4* acc0, f32x4* acc1) {
    int wave = t >> 6, lane = t & 63, r = lane & 15, g = lane >> 4;
    const int TPW = (NT + 3) / 4;
#pragma unroll
    for (int i = 0; i < TPW; ++i) {
        acc0[i] = (f32x4){0.f, 0.f, 0.f, 0.f};
        acc1[i] = (f32x4){0.f, 0.f, 0.f, 0.f};
    }
    for (int ks = 0; ks < ksteps; ++ks) {
        f16x8 a0 = *(const f16x8*)(Ah + r * astride + ks * 32 + g * 8);
        f16x8 a1 = *(const f16x8*)(Ah + (16 + r) * astride + ks * 32 + g * 8);
#pragma unroll
        for (int i = 0; i < TPW; ++i) {
            int nt = wave + 4 * i;
            if (nt < NT) {
                f16x8 b = *(const f16x8*)(Wt + ((size_t)(nt * ksteps + ks) * 64 + lane) * 8);
                acc0[i] = __builtin_amdgcn_mfma_f32_16x16x32_f16(a0, b, acc0[i], 0, 0, 0);
                acc1[i] = __builtin_amdgcn_mfma_f32_16x16x32_f16(a1, b, acc1[i], 0, 0, 0);
            }
        }
    }
}

// gather lat_in -> Ah cols 0..159 (f16), compute s_cut (p-space when eord)
__device__ __forceinline__ void gather_latin(
    const float* __restrict__ nodeinv, const float* __restrict__ edgeinv,
    const float* __restrict__ elen, const int* __restrict__ eidx,
    const int* __restrict__ eord, int e0, int t, _Float16* Ah, float* s_cut) {
    if (t < EB) {
        int e = eord ? eord[e0 + t] : (e0 + t);
        s_cut[t] = cutf(elen[e]);
    }
    for (int i = t; i < EB * 160; i += 256) {
        int ee = i / 160, k = i - ee * 160;
        int e = eord ? eord[e0 + ee] : (e0 + ee);
        float v;
        if (k < 64)       v = nodeinv[eidx[e] * 64 + k];
        else if (k < 128) v = nodeinv[eidx[NE + e] * 64 + (k - 64)];
        else if (k < 136) v = edgeinv[(size_t)e * 8 + (k - 128)];
        else              v = 0.f;
        Ah[ee * AST + k] = (_Float16)v;
    }
}

// lat0 (2 GEMMs) -> Ah cols 0..255 f16
__device__ __forceinline__ void lat0_mfma2(const _Float16* __restrict__ W2aT,
                                           const _Float16* __restrict__ W2bT,
                                           int t, _Float16* Ah, _Float16* AhB,
                                           const float* s_cut) {
    int wave = t >> 6, lane = t & 63, r = lane & 15, g = lane >> 4;
    f32x4 acc0[4], acc1[4];
    mfma_gemm2<16>(5, Ah, AST, W2aT, t, acc0, acc1);
#pragma unroll
    for (int i = 0; i < 4; ++i) {
        int nt = wave + 4 * i;
#pragma unroll
        for (int i2 = 0; i2 < 4; ++i2) {
            AhB[(g * 4 + i2) * BST + nt * 16 + r] = (_Float16)silu(acc0[i][i2]);
            AhB[(16 + g * 4 + i2) * BST + nt * 16 + r] = (_Float16)silu(acc1[i][i2]);
        }
    }
    __syncthreads();
    mfma_gemm2<16>(8, AhB, BST, W2bT, t, acc0, acc1);
#pragma unroll
    for (int i = 0; i < 4; ++i) {
        int nt = wave + 4 * i;
#pragma unroll
        for (int i2 = 0; i2 < 4; ++i2) {
            int ro = g * 4 + i2, col = nt * 16 + r;
            Ah[ro * AST + col] = (_Float16)(s_cut[ro] * silu(acc0[i][i2]));
            Ah[(16 + ro) * AST + col] = (_Float16)(s_cut[16 + ro] * silu(acc1[i][i2]));
        }
    }
    __syncthreads();
}

// lnorm(featN[center]) -> Ah cols 256..351 f16
__device__ __forceinline__ void gather_lnorm(const float* __restrict__ featN,
                                             const int* __restrict__ eidx,
                                             const int* __restrict__ eord,
                                             int e0, int t, _Float16* Ah) {
    for (int i = t; i < EB * 96; i += 256) {
        int ee = i / 96, rem = i - ee * 96;
        int l = rem >> 5, kk = rem & 31;
        int off = (l == 0) ? 0 : ((l == 1) ? 1 : 4);
        int d = (l == 0) ? 1 : ((l == 1) ? 3 : 5);
        int e = eord ? eord[e0 + ee] : (e0 + ee);
        const float* f = featN + (size_t)eidx[e] * 288 + kk;
        float s = 1e-8f;
        for (int mm = off; mm < off + d; ++mm) { float x = f[mm * 32]; s = fmaf(x, x, s); }
        Ah[ee * AST + 256 + rem] = (_Float16)sqrtf(s);
    }
}

// unsorted atomic scatter into env (fallback)
__device__ __forceinline__ void scatter_env(const float* __restrict__ edge_attr,
                                            const int* __restrict__ eidx,
                                            const float* s_w, const float* s_cut,
                                            int e0, int t, float* __restrict__ env) {
    for (int i = t; i < EB * 32; i += 256) {
        int el = i >> 5, k = i & 31;
        int e = e0 + el;
        float cw = s_cut[el];
        int n = eidx[e];
        float w0 = s_w[el * 96 + k * 3 + 0] * cw;
        float w1 = s_w[el * 96 + k * 3 + 1] * cw;
        float w2 = s_w[el * 96 + k * 3 + 2] * cw;
        float* dst = env + (size_t)n * 288 + k;
#pragma unroll
        for (int m = 0; m < 9; ++m) {
            float w = (m == 0) ? w0 : ((m < 4) ? w1 : w2);
            atomicAdd(dst + m * 32, edge_attr[(size_t)e * 9 + m] * w);
        }
    }
}

// sorted segmented-flush scatter: s_sh = sh*cut, s_nid nondecreasing
__device__ __forceinline__ void scatter_sorted(const float* s_sh, const int* s_nid,
                                               const float* s_w, int t,
                                               float* __restrict__ env) {
    for (int pp = t; pp < 288; pp += 256) {
        int m = pp >> 5, k = pp & 31;
        int l = (m == 0) ? 0 : ((m < 4) ? 1 : 2);
        float run = 0.f;
        int nprev = s_nid[0];
        for (int el = 0; el < EB; ++el) {
            int nid = s_nid[el];
            if (nid != nprev) {
                atomicAdd(&env[(size_t)nprev * 288 + m * 32 + k], run);
                run = 0.f;
                nprev = nid;
            }
            run = fmaf(s_sh[el * 9 + m], s_w[el * 96 + k * 3 + l], run);
        }
        atomicAdd(&env[(size_t)nprev * 288 + m * 32 + k], run);
    }
}

// NT=6 epilogue -> s_w (f32)
__device__ __forceinline__ void epi6_f32(const f32x4* acc0, const f32x4* acc1, int t,
                                         float* s_w) {
    int wave = t >> 6, lane = t & 63, r = lane & 15, g = lane >> 4;
#pragma unroll
    for (int i = 0; i < 2; ++i) {
        int nt = wave + 4 * i;
        if (nt < 6) {
#pragma unroll
            for (int i2 = 0; i2 < 4; ++i2) {
                s_w[(g * 4 + i2) * 96 + nt * 16 + r] = acc0[i][i2];
                s_w[(16 + g * 4 + i2) * 96 + nt * 16 + r] = acc1[i][i2];
            }
        }
    }
}

// ---------------------------------------------------------------- K1: lat0 -> persist lat0h + w0h + scatter round 0
__global__ __launch_bounds__(256) void k1_lat_scatter0(
    const float* __restrict__ nodeinv, const float* __restrict__ edgeinv,
    const float* __restrict__ elen, const float* __restrict__ edge_attr,
    const int* __restrict__ eidx, const _Float16* __restrict__ W2aT,
    const _Float16* __restrict__ W2bT, const _Float16* __restrict__ Wenv0T,
    float* __restrict__ env, _Float16* __restrict__ lat0h,
    _Float16* __restrict__ w0h, const int* __restrict__ eord) {
    __shared__ alignas(16) _Float16 Ah[EB * AST];
    __shared__ alignas(16) _Float16 AhB[EB * BST];
    __shared__ float s_cut[EB];
    __shared__ float s_sh[EB * 9];
    __shared__ int s_nid[EB];
    float* s_w = (float*)AhB;  // overlay: AhB dead after lat0
    int t = threadIdx.x;
    int e0 = blockIdx.x * EB;
    int wave = t >> 6, lane = t & 63, r = lane & 15, g = lane >> 4;
    gather_latin(nodeinv, edgeinv, elen, eidx, eord, e0, t, Ah, s_cut);
    __syncthreads();
    lat0_mfma2(W2aT, W2bT, t, Ah, AhB, s_cut);
    // persist lat0 (f16), p-indexed
    for (int i = t; i < EB * 32; i += 256) {
        int ee = i >> 5, c8 = (i & 31) * 8;
        *(f16x8*)(lat0h + (size_t)(e0 + ee) * 256 + c8) =
            *(const f16x8*)(Ah + ee * AST + c8);
    }
    // combined Wenv0 GEMM (12 n-tiles over 192 cols)
    f32x4 acc0[3], acc1[3];
    mfma_gemm2<12>(8, Ah, AST, Wenv0T, t, acc0, acc1);
#pragma unroll
    for (int i = 0; i < 3; ++i) {
        int nt = wave + 4 * i;
        if (nt < 6) {
#pragma unroll
            for (int i2 = 0; i2 < 4; ++i2) {
                w0h[(size_t)(e0 + g * 4 + i2) * 96 + nt * 16 + r] = (_Float16)acc0[i][i2];
                w0h[(size_t)(e0 + 16 + g * 4 + i2) * 96 + nt * 16 + r] = (_Float16)acc1[i][i2];
            }
        } else {
#pragma unroll
            for (int i2 = 0; i2 < 4; ++i2) {
                s_w[(g * 4 + i2) * 96 + (nt - 6) * 16 + r] = acc0[i][i2];
                s_w[(16 + g * 4 + i2) * 96 + (nt - 6) * 16 + r] = acc1[i][i2];
            }
        }
    }
    if (eord) {
        if (t < EB) s_nid[t] = eidx[eord[e0 + t]];
        for (int i = t; i < EB * 9; i += 256) {
            int el = i / 9, m = i - el * 9;
            s_sh[i] = edge_attr[(size_t)eord[e0 + el] * 9 + m] * s_cut[el];
        }
    }
    __syncthreads();
    if (eord) scatter_sorted(s_sh, s_nid, s_w, t, env);
    else      scatter_env(edge_attr, eidx, s_w, s_cut, e0, t, env);
}

// ---------------------------------------------------------------- node transform (env input)
__global__ __launch_bounds__(288) void k_node(
    const float* envin, const float* __restrict__ nodeinv,
    const float* __restrict__ Wenvlin, const float* __restrict__ Wprod,
    const float* __restrict__ Wfeat, float* featOut) {
    __shared__ float s_env[288];
    __shared__ float s_inv[64];
    __shared__ float s_mix[288];
    __shared__ float s_ew[96];
    int n = blockIdx.x;
    int t = threadIdx.x;
    s_env[t] = envin[(size_t)n * 288 + t] * (1.0f / 32.0f);
    if (t < 64) s_inv[t] = nodeinv[n * 64 + t];
    __syncthreads();
    int m = t >> 5, j = t & 31;
    int l = (m == 0) ? 0 : ((m < 4) ? 1 : 2);
    float a = 0.f;
    for (int k = 0; k < 32; ++k) a = fmaf(s_env[m * 32 + k], Wenvlin[l * 1024 + k * 32 + j], a);
    if (t < 96) {
        int c = t >> 5, jj = t & 31;
        float b = 0.f;
        for (int tt = 0; tt < 64; ++tt) b = fmaf(s_inv[tt], Wprod[c * 2048 + tt * 32 + jj], b);
        s_ew[t] = b;
    }
    s_mix[t] = a;
    __syncthreads();
    float s = s_mix[j];
    float p = s_mix[t] * (s_ew[j] + s_ew[32 + j] * s + s_ew[64 + j] * s * s);
    __syncthreads();
    s_env[t] = p;
    __syncthreads();
    float o = 0.f;
    for (int jl = 0; jl < 32; ++jl) o = fmaf(s_env[m * 32 + jl], Wfeat[l * 1024 + jl * 32 + j], o);
    featOut[(size_t)n * 288 + t] = o;
}

// ---------------------------------------------------------------- K3: load lat0h -> lat1 (overwrite) -> Wenv1 -> scatter
__global__ __launch_bounds__(256) void k3_update_scatter1(
    const float* __restrict__ elen, const float* __restrict__ edge_attr,
    const int* __restrict__ eidx, const _Float16* __restrict__ Wl1aT,
    const _Float16* __restrict__ Wl1bT, const _Float16* __restrict__ Wenv1T,
    const float* __restrict__ featN0, float* __restrict__ env,
    _Float16* __restrict__ lat01h, const int* __restrict__ eord) {
    __shared__ alignas(16) _Float16 Ah[EB * AST];
    __shared__ alignas(16) _Float16 AhB[EB * BST];
    __shared__ float s_cut[EB];
    __shared__ float s_sh[EB * 9];
    __shared__ int s_nid[EB];
    float* s_w = (float*)AhB;
    int t = threadIdx.x;
    int e0 = blockIdx.x * EB;
    int wave = t >> 6, lane = t & 63, r = lane & 15, g = lane >> 4;
    if (t < EB) {
        int e = eord ? eord[e0 + t] : (e0 + t);
        s_cut[t] = cutf(elen[e]);
    }
    for (int i = t; i < EB * 32; i += 256) {
        int ee = i >> 5, c8 = (i & 31) * 8;
        *(f16x8*)(Ah + ee * AST + c8) =
            *(const f16x8*)(lat01h + (size_t)(e0 + ee) * 256 + c8);
    }
    gather_lnorm(featN0, eidx, eord, e0, t, Ah);
    __syncthreads();
    f32x4 acc0[4], acc1[4];
    mfma_gemm2<16>(11, Ah, AST, Wl1aT, t, acc0, acc1);
#pragma unroll
    for (int i = 0; i < 4; ++i) {
        int nt = wave + 4 * i;
#pragma unroll
        for (int i2 = 0; i2 < 4; ++i2) {
            AhB[(g * 4 + i2) * BST + nt * 16 + r] = (_Float16)silu(acc0[i][i2]);
            AhB[(16 + g * 4 + i2) * BST + nt * 16 + r] = (_Float16)silu(acc1[i][i2]);
        }
    }
    __syncthreads();
    mfma_gemm2<16>(8, AhB, BST, Wl1bT, t, acc0, acc1);
#pragma unroll
    for (int i = 0; i < 4; ++i) {
        int nt = wave + 4 * i;
#pragma unroll
        for (int i2 = 0; i2 < 4; ++i2) {
            int ro = g * 4 + i2, col = nt * 16 + r;
            float v0 = 0.8944271909999159f * (float)Ah[ro * AST + col] +
                       0.4472135954999579f * s_cut[ro] * silu(acc0[i][i2]);
            _Float16 h0 = (_Float16)v0;
            Ah[ro * AST + col] = h0;
            lat01h[(size_t)(e0 + ro) * 256 + col] = h0;
            float v1 = 0.8944271909999159f * (float)Ah[(16 + ro) * AST + col] +
                       0.4472135954999579f * s_cut[16 + ro] * silu(acc1[i][i2]);
            _Float16 h1 = (_Float16)v1;
            Ah[(16 + ro) * AST + col] = h1;
            lat01h[(size_t)(e0 + 16 + ro) * 256 + col] = h1;
        }
    }
    __syncthreads();
    mfma_gemm2<6>(8, Ah, AST, Wenv1T, t, acc0, acc1);
    epi6_f32(acc0, acc1, t, s_w);
    if (eord) {
        if (t < EB) s_nid[t] = eidx[eord[e0 + t]];
        for (int i = t; i < EB * 9; i += 256) {
            int el = i / 9, m = i - el * 9;
            s_sh[i] = edge_attr[(size_t)eord[e0 + el] * 9 + m] * s_cut[el];
        }
    }
    __syncthreads();
    if (eord) scatter_sorted(s_sh, s_nid, s_w, t, env);
    else      scatter_env(edge_attr, eidx, s_w, s_cut, e0, t, env);
}

// ---------------------------------------------------------------- K5 fast v9: barrier-free direct-global B, 4 waves/SIMD
#define FEB 128
__global__ __launch_bounds__(256, 4) void k5_fast(
    const float* __restrict__ edge_attr, const int* __restrict__ eidx,
    const _Float16* __restrict__ lat1h, const _Float16* __restrict__ w0h,
    const _Float16* __restrict__ Bfin3, const _Float16* __restrict__ Wro1T32,
    const float* __restrict__ Wro2, const float* __restrict__ featN1,
    const int* __restrict__ eord, float* __restrict__ out) {
    __shared__ alignas(16) _Float16 s_S[FEB * SST]; // 24.5 KB: S, then scal overlay
    int t = threadIdx.x;
    int e0 = blockIdx.x * FEB;
    int wave = t >> 6, lane = t & 63;
    int r31 = lane & 31, kh5 = lane >> 5;
    // ---- S gather
    for (int i = t; i < FEB * 96; i += 256) {
        int ee = i / 96, rem = i - ee * 96;
        int l = rem >> 5, kk = rem & 31;
        int off = (l == 0) ? 0 : ((l == 1) ? 1 : 4);
        int d = (l == 0) ? 1 : ((l == 1) ? 3 : 5);
        int e = eord ? eord[e0 + ee] : (e0 + ee);
        const float* f = featN1 + (size_t)eidx[e] * 288 + kk;
        float s = 0.f;
        for (int mm = off; mm < off + d; ++mm)
            s = fmaf(f[mm * 32], edge_attr[(size_t)e * 9 + mm], s);
        s_S[ee * SST + rem] = (_Float16)s;
    }
    // ---- lat1 frags (used as MFMA *B* in contraction, *A* in readout)
    f16x8 a2[16];
#pragma unroll
    for (int q = 0; q < 16; ++q)
        a2[q] = *(const f16x8*)(lat1h + (size_t)(e0 + wave * 32 + r31) * 256 +
                                q * 16 + kh5 * 8);
    __syncthreads();  // s_S visible to all waves
    const f32x16 z16 = {0.f, 0.f, 0.f, 0.f, 0.f, 0.f, 0.f, 0.f,
                        0.f, 0.f, 0.f, 0.f, 0.f, 0.f, 0.f, 0.f};
    f32x16 acc[3];
#pragma unroll
    for (int l = 0; l < 3; ++l) acc[l] = z16;
#pragma unroll
    for (int l = 0; l < 3; ++l) {
#pragma unroll 1
        for (int ke = 0; ke < 32; ++ke) {
            const _Float16* bs = Bfin3 + (size_t)(l * 32 + ke) * 8192 + lane * 8;
            float sf = (float)s_S[(wave * 32 + r31) * SST + l * 32 + ke];
            f32x16 ac = z16;
#pragma unroll
            for (int q = 0; q < 16; ++q) {
                f16x8 bf = *(const f16x8*)(bs + q * 512);  // direct from L2
                // D^T: A = Wfin frag (rows=j), B = lat1 (cols=e)
                ac = __builtin_amdgcn_mfma_f32_32x32x16_f16(bf, a2[q], ac, 0, 0, 0);
            }
#pragma unroll
            for (int reg = 0; reg < 16; ++reg)
                acc[l][reg] = fmaf(sf, ac[reg], acc[l][reg]);  // deferred S (f32)
        }
    }
    // ---- apply w0 -> scal f16 (D^T: row=j from reg, col=e per lane)
    int pe = e0 + wave * 32 + r31;  // this lane's edge (p-space)
#pragma unroll
    for (int l = 0; l < 3; ++l) {
#pragma unroll
        for (int reg = 0; reg < 16; ++reg) {
            int jrow = (reg & 3) + 8 * (reg >> 2) + 4 * kh5;  // 32x32 D layout (m74/m101)
            float w0 = (float)w0h[(size_t)pe * 96 + jrow * 3 + l];
            s_S[(wave * 32 + r31) * SST + l * 32 + jrow] = (_Float16)(acc[l][reg] * w0);
        }
    }
    __syncthreads();
    // ---- readout: 32x32 tiles, rows = edges (a2 as A), 8 col-blocks
    float v16[16];
#pragma unroll
    for (int reg = 0; reg < 16; ++reg) v16[reg] = 0.f;
#pragma unroll 1
    for (int cb = 0; cb < 8; ++cb) {
        f32x16 racc = z16;
#pragma unroll
        for (int ks2 = 0; ks2 < 22; ++ks2) {
            f16x8 af = (ks2 < 16)
                ? a2[ks2]
                : *(const f16x8*)&s_S[(wave * 32 + r31) * SST + (ks2 - 16) * 16 + kh5 * 8];
            f16x8 b = *(const f16x8*)(Wro1T32 + ((size_t)(cb * 22 + ks2) * 512 + lane * 8));
            racc = __builtin_amdgcn_mfma_f32_32x32x16_f16(af, b, racc, 0, 0, 0);
        }
        float w2 = Wro2[cb * 32 + r31];
#pragma unroll
        for (int reg = 0; reg < 16; ++reg) v16[reg] += silu(racc[reg]) * w2;
    }
#pragma unroll
    for (int off = 1; off < 32; off <<= 1)
#pragma unroll
        for (int reg = 0; reg < 16; ++reg) v16[reg] += __shfl_xor(v16[reg], off);
    if (r31 == 0) {
#pragma unroll
        for (int reg = 0; reg < 16; ++reg) {
            int row = (reg & 3) + 8 * (reg >> 2) + 4 * kh5;
            int pidx = e0 + wave * 32 + row;
            int e = eord ? eord[pidx] : pidx;
            out[e] = v16[reg];
        }
    }
}

// ----------------------------------------------------------------
extern "C" void kernel_launch(void* const* d_in, const int* in_sizes, int n_in,
                              void* d_out, int out_size, void* d_ws, size_t ws_size,
                              hipStream_t stream) {
    (void)in_sizes; (void)n_in; (void)out_size;
    const float* edge_attr = (const float*)d_in[0];
    const float* edge_len  = (const float*)d_in[1];
    const float* edge_inv  = (const float*)d_in[2];
    const float* node_inv  = (const float*)d_in[3];
    const float* W2a     = (const float*)d_in[4];
    const float* W2b     = (const float*)d_in[5];
    const float* Wl1a    = (const float*)d_in[6];
    const float* Wl1b    = (const float*)d_in[7];
    const float* Wenv0   = (const float*)d_in[8];
    const float* Wenv1   = (const float*)d_in[9];
    const float* Wenvlin = (const float*)d_in[10];
    const float* Wprod   = (const float*)d_in[11];
    const float* Wfeat   = (const float*)d_in[12];
    const float* Wfinlat = (const float*)d_in[13];
    const float* Wro1    = (const float*)d_in[14];
    const float* Wro2    = (const float*)d_in[15];
    const int* eidx      = (const int*)d_in[16];
    float* out = (float*)d_out;

    _Float16* p = (_Float16*)d_ws;
    _Float16* Bfin3   = p; p += 786432;
    _Float16* W2aT    = p; p += 40960;
    _Float16* W2bT    = p; p += 65536;
    _Float16* Wenv0T  = p; p += 49152;   // NT=12 combined (cols 0..191)
    _Float16* Wenv1T  = p; p += 24576;
    _Float16* Wl1aT   = p; p += 90112;
    _Float16* Wl1bT   = p; p += 65536;
    _Float16* Wro1T32 = p; p += 90112;
    float* env    = (float*)p;
    float* featN0 = env + (size_t)NNODES * 288;
    char* after = (char*)(featN0 + (size_t)NNODES * 288);
    size_t need_base = (size_t)(after - (char*)d_ws);
    if (ws_size < need_base) return;
    _Float16* lat01h = (_Float16*)after;                      // NE*256 f16 (lat0 then lat1)
    _Float16* w0h    = lat01h + (size_t)NE * 256;             // NE*96 f16
    size_t need = need_base + (size_t)NE * (256 + 96) * sizeof(_Float16);
    if (ws_size < need) return;  // proven to fit since R7
    int* eord   = (int*)((char*)d_ws + need);                 // NE ints
    int* seg    = eord + NE;                                  // NNODES+1
    int* cursor = seg + NNODES + 1;                           // NNODES
    size_t need_sorted = need + (size_t)(NE + 2 * NNODES + 1) * sizeof(int);
    bool sorted = (ws_size >= need_sorted);
    const int* eordk = sorted ? eord : nullptr;

    const int ENV_N = NNODES * 288;
    k_packfin3<<<3072, 256, 0, stream>>>(Wfinlat, Bfin3);
    k_packf<<<160, 256, 0, stream>>>(W2a, W2aT, 136, 5, 16, 256, 0);
    k_packf<<<256, 256, 0, stream>>>(W2b, W2bT, 256, 8, 16, 256, 0);
    k_packf<<<192, 256, 0, stream>>>(Wenv0, Wenv0T, 256, 8, 12, 192, 0);
    k_packf<<<96, 256, 0, stream>>>(Wenv1, Wenv1T, 256, 8, 6, 96, 0);
    k_packf<<<352, 256, 0, stream>>>(Wl1a, Wl1aT, 352, 11, 16, 256, 0);
    k_packf<<<256, 256, 0, stream>>>(Wl1b, Wl1bT, 256, 8, 16, 256, 0);
    k_packro5<<<352, 256, 0, stream>>>(Wro1, Wro1T32);

    if (sorted) {
        k_zero<<<(NNODES + 255) / 256, 256, 0, stream>>>((float*)cursor, NNODES);
        k_hist<<<NE / 256, 256, 0, stream>>>(eidx, cursor);   // cursor = counts
        k_scan<<<1, 256, 0, stream>>>(cursor, seg, cursor);   // seg + cursor (aliased, fixed)
        k_place<<<NE / 256, 256, 0, stream>>>(eidx, cursor, eord);
    }

    k_zero<<<(ENV_N + 255) / 256, 256, 0, stream>>>(env, ENV_N);
    k1_lat_scatter0<<<NBLK, 256, 0, stream>>>(node_inv, edge_inv, edge_len, edge_attr,
                                              eidx, W2aT, W2bT, Wenv0T, env, lat01h, w0h,
                                              eordk);
    k_node<<<NNODES, 288, 0, stream>>>(env, node_inv, Wenvlin, Wprod, Wfeat, featN0);
    k_zero<<<(ENV_N + 255) / 256, 256, 0, stream>>>(env, ENV_N);
    k3_update_scatter1<<<NBLK, 256, 0, stream>>>(edge_len, edge_attr, eidx,
                                                 Wl1aT, Wl1bT, Wenv1T, featN0, env, lat01h,
                                                 eordk);
    k_node<<<NNODES, 288, 0, stream>>>(env, node_inv, Wenvlin + 3072, Wprod + 6144,
                                       Wfeat + 3072, env);  // in-place: env1 -> featN1
    k5_fast<<<NE / FEB, 256, 0, stream>>>(edge_attr, eidx, lat01h, w0h, Bfin3, Wro1T32,
                                          Wro2, env, eordk, out);
}

// Round 18
// 2695.041 us; speedup vs baseline: 1.2247x; 1.2247x over previous
//
#include <hip/hip_runtime.h>
#include <math.h>

#define NE 320000
#define NNODES 10000
#define EB 32
#define NBLK (NE / EB)
#define AST 360   // Ah stride (f16 elems)
#define BST 264   // AhB stride (f16 elems)
#define SST 98    // padded S/scal stride (f16)

typedef _Float16 f16x8 __attribute__((ext_vector_type(8)));
typedef float f32x4 __attribute__((ext_vector_type(4)));
typedef float f32x16 __attribute__((ext_vector_type(16)));

__device__ __forceinline__ float silu(float x) { return x / (1.0f + __expf(-x)); }
__device__ __forceinline__ float cutf(float len) {
    float x = len * (1.0f / 6.0f);
    float x2 = x * x, x6 = x2 * x2 * x2;
    float f = 1.0f - 28.0f * x6 + 48.0f * x6 * x - 21.0f * x6 * x2;
    return (x < 1.0f) ? f : 0.0f;
}

// ---------------------------------------------------------------- zero
__global__ __launch_bounds__(256) void k_zero(float* __restrict__ p, int n) {
    int i = blockIdx.x * 256 + threadIdx.x;
    if (i < n) p[i] = 0.f;
}

// ---------------------------------------------------------------- sort prep
__global__ __launch_bounds__(256) void k_hist(const int* __restrict__ eidx,
                                              int* __restrict__ cnt) {
    int e = blockIdx.x * 256 + threadIdx.x;
    if (e < NE) atomicAdd(&cnt[eidx[e]], 1);
}

__global__ __launch_bounds__(256) void k_scan(const int* __restrict__ cnt,
                                              int* __restrict__ seg,
                                              int* __restrict__ cursor) {
    __shared__ int part[256];
    __shared__ int base[256];
    int t = threadIdx.x;
    int start = t * 40;
    int s = 0;
    for (int i = 0; i < 40; ++i) {
        int idx = start + i;
        if (idx < NNODES) s += cnt[idx];
    }
    part[t] = s;
    __syncthreads();
    if (t == 0) {
        int run = 0;
        for (int i = 0; i < 256; ++i) { base[i] = run; run += part[i]; }
    }
    __syncthreads();
    int run = base[t];
    for (int i = 0; i < 40; ++i) {
        int idx = start + i;
        if (idx < NNODES) {
            int c = cnt[idx];       // read BEFORE overwriting (cnt may alias cursor)
            seg[idx] = run;
            cursor[idx] = run;
            run += c;
        }
    }
    if (t == 0) seg[NNODES] = NE;
}

__global__ __launch_bounds__(256) void k_place(const int* __restrict__ eidx,
                                               int* __restrict__ cursor,
                                               int* __restrict__ eord) {
    int e = blockIdx.x * 256 + threadIdx.x;
    if (e < NE) {
        int p = atomicAdd(&cursor[eidx[e]], 1);
        eord[p] = e;
    }
}

// ---------------------------------------------------------------- fragment-major pack for MLP weights (16x16 path)
__global__ __launch_bounds__(256) void k_packf(const float* __restrict__ src,
                                               _Float16* __restrict__ dst,
                                               int K, int KS, int NT, int stride,
                                               int colOff) {
    int i = blockIdx.x * 256 + threadIdx.x;
    if (i >= NT * KS * 512) return;
    int j = i & 7, lane = (i >> 3) & 63;
    int blk = i >> 9;
    int ks = blk % KS, nt = blk / KS;
    int k = ks * 32 + (lane >> 4) * 8 + j;
    int n = colOff + nt * 16 + (lane & 15);
    dst[i] = (k < K) ? (_Float16)src[(size_t)k * stride + n] : (_Float16)0.f;
}

// ---------------------------------------------------------------- stage-major pack of Wfinlat (32x32 pipeline, R9-proven)
__global__ __launch_bounds__(256) void k_packfin3(const float* __restrict__ W,
                                                  _Float16* __restrict__ dst) {
    int i = blockIdx.x * 256 + threadIdx.x;  // < 786432
    int j = i & 7, lane = (i >> 3) & 63, q = (i >> 9) & 15, s = i >> 13;
    int l = s >> 5, ke = s & 31;
    int c = q * 16 + (lane >> 5) * 8 + j;
    int n = l * 1024 + ke * 32 + (lane & 31);
    dst[i] = (_Float16)W[(size_t)c * 3072 + n];
}

// ---------------------------------------------------------------- 32x32x16 pack of Wro1 (readout B)
__global__ __launch_bounds__(256) void k_packro5(const float* __restrict__ W,
                                                 _Float16* __restrict__ dst) {
    int i = blockIdx.x * 256 + threadIdx.x;  // < 90112
    if (i >= 90112) return;
    int j = i & 7, lane = (i >> 3) & 63, u = i >> 9;
    int cb = u / 22, ks2 = u - cb * 22;
    int k = ks2 * 16 + (lane >> 5) * 8 + j;
    int n = cb * 32 + (lane & 31);
    dst[i] = (_Float16)W[(size_t)k * 256 + n];
}

// ---------------------------------------------------------------- MFMA GEMM, 32 edges (2 m-tiles), frag-major B
template <int NT>
__device__ __forceinline__ void mfma_gemm2(int ksteps, const _Float16* Ah, int astride,
                                           const _Float16* __restrict__ Wt, int t,
                                           f32x4* acc0, f32x4* acc1) {
    int wave = t >> 6, lane = t & 63, r = lane & 15, g = lane >> 4;
    const int TPW = (NT + 3) / 4;
#pragma unroll
    for (int i = 0; i < TPW; ++i) {
        acc0[i] = (f32x4){0.f, 0.f, 0.f, 0.f};
        acc1[i] = (f32x4){0.f, 0.f, 0.f, 0.f};
    }
    for (int ks = 0; ks < ksteps; ++ks) {
        f16x8 a0 = *(const f16x8*)(Ah + r * astride + ks * 32 + g * 8);
        f16x8 a1 = *(const f16x8*)(Ah + (16 + r) * astride + ks * 32 + g * 8);
#pragma unroll
        for (int i = 0; i < TPW; ++i) {
            int nt = wave + 4 * i;
            if (nt < NT) {
                f16x8 b = *(const f16x8*)(Wt + ((size_t)(nt * ksteps + ks) * 64 + lane) * 8);
                acc0[i] = __builtin_amdgcn_mfma_f32_16x16x32_f16(a0, b, acc0[i], 0, 0, 0);
                acc1[i] = __builtin_amdgcn_mfma_f32_16x16x32_f16(a1, b, acc1[i], 0, 0, 0);
            }
        }
    }
}

// gather lat_in -> Ah cols 0..159 (f16), compute s_cut (p-space when eord)
__device__ __forceinline__ void gather_latin(
    const float* __restrict__ nodeinv, const float* __restrict__ edgeinv,
    const float* __restrict__ elen, const int* __restrict__ eidx,
    const int* __restrict__ eord, int e0, int t, _Float16* Ah, float* s_cut) {
    if (t < EB) {
        int e = eord ? eord[e0 + t] : (e0 + t);
        s_cut[t] = cutf(elen[e]);
    }
    for (int i = t; i < EB * 160; i += 256) {
        int ee = i / 160, k = i - ee * 160;
        int e = eord ? eord[e0 + ee] : (e0 + ee);
        float v;
        if (k < 64)       v = nodeinv[eidx[e] * 64 + k];
        else if (k < 128) v = nodeinv[eidx[NE + e] * 64 + (k - 64)];
        else if (k < 136) v = edgeinv[(size_t)e * 8 + (k - 128)];
        else              v = 0.f;
        Ah[ee * AST + k] = (_Float16)v;
    }
}

// lat0 (2 GEMMs) -> Ah cols 0..255 f16
__device__ __forceinline__ void lat0_mfma2(const _Float16* __restrict__ W2aT,
                                           const _Float16* __restrict__ W2bT,
                                           int t, _Float16* Ah, _Float16* AhB,
                                           const float* s_cut) {
    int wave = t >> 6, lane = t & 63, r = lane & 15, g = lane >> 4;
    f32x4 acc0[4], acc1[4];
    mfma_gemm2<16>(5, Ah, AST, W2aT, t, acc0, acc1);
#pragma unroll
    for (int i = 0; i < 4; ++i) {
        int nt = wave + 4 * i;
#pragma unroll
        for (int i2 = 0; i2 < 4; ++i2) {
            AhB[(g * 4 + i2) * BST + nt * 16 + r] = (_Float16)silu(acc0[i][i2]);
            AhB[(16 + g * 4 + i2) * BST + nt * 16 + r] = (_Float16)silu(acc1[i][i2]);
        }
    }
    __syncthreads();
    mfma_gemm2<16>(8, AhB, BST, W2bT, t, acc0, acc1);
#pragma unroll
    for (int i = 0; i < 4; ++i) {
        int nt = wave + 4 * i;
#pragma unroll
        for (int i2 = 0; i2 < 4; ++i2) {
            int ro = g * 4 + i2, col = nt * 16 + r;
            Ah[ro * AST + col] = (_Float16)(s_cut[ro] * silu(acc0[i][i2]));
            Ah[(16 + ro) * AST + col] = (_Float16)(s_cut[16 + ro] * silu(acc1[i][i2]));
        }
    }
    __syncthreads();
}

// lnorm(featN[center]) -> Ah cols 256..351 f16
__device__ __forceinline__ void gather_lnorm(const float* __restrict__ featN,
                                             const int* __restrict__ eidx,
                                             const int* __restrict__ eord,
                                             int e0, int t, _Float16* Ah) {
    for (int i = t; i < EB * 96; i += 256) {
        int ee = i / 96, rem = i - ee * 96;
        int l = rem >> 5, kk = rem & 31;
        int off = (l == 0) ? 0 : ((l == 1) ? 1 : 4);
        int d = (l == 0) ? 1 : ((l == 1) ? 3 : 5);
        int e = eord ? eord[e0 + ee] : (e0 + ee);
        const float* f = featN + (size_t)eidx[e] * 288 + kk;
        float s = 1e-8f;
        for (int mm = off; mm < off + d; ++mm) { float x = f[mm * 32]; s = fmaf(x, x, s); }
        Ah[ee * AST + 256 + rem] = (_Float16)sqrtf(s);
    }
}

// unsorted atomic scatter into env (fallback)
__device__ __forceinline__ void scatter_env(const float* __restrict__ edge_attr,
                                            const int* __restrict__ eidx,
                                            const float* s_w, const float* s_cut,
                                            int e0, int t, float* __restrict__ env) {
    for (int i = t; i < EB * 32; i += 256) {
        int el = i >> 5, k = i & 31;
        int e = e0 + el;
        float cw = s_cut[el];
        int n = eidx[e];
        float w0 = s_w[el * 96 + k * 3 + 0] * cw;
        float w1 = s_w[el * 96 + k * 3 + 1] * cw;
        float w2 = s_w[el * 96 + k * 3 + 2] * cw;
        float* dst = env + (size_t)n * 288 + k;
#pragma unroll
        for (int m = 0; m < 9; ++m) {
            float w = (m == 0) ? w0 : ((m < 4) ? w1 : w2);
            atomicAdd(dst + m * 32, edge_attr[(size_t)e * 9 + m] * w);
        }
    }
}

// sorted segmented-flush scatter: s_sh = sh*cut, s_nid nondecreasing
__device__ __forceinline__ void scatter_sorted(const float* s_sh, const int* s_nid,
                                               const float* s_w, int t,
                                               float* __restrict__ env) {
    for (int pp = t; pp < 288; pp += 256) {
        int m = pp >> 5, k = pp & 31;
        int l = (m == 0) ? 0 : ((m < 4) ? 1 : 2);
        float run = 0.f;
        int nprev = s_nid[0];
        for (int el = 0; el < EB; ++el) {
            int nid = s_nid[el];
            if (nid != nprev) {
                atomicAdd(&env[(size_t)nprev * 288 + m * 32 + k], run);
                run = 0.f;
                nprev = nid;
            }
            run = fmaf(s_sh[el * 9 + m], s_w[el * 96 + k * 3 + l], run);
        }
        atomicAdd(&env[(size_t)nprev * 288 + m * 32 + k], run);
    }
}

// NT=6 epilogue -> s_w (f32)
__device__ __forceinline__ void epi6_f32(const f32x4* acc0, const f32x4* acc1, int t,
                                         float* s_w) {
    int wave = t >> 6, lane = t & 63, r = lane & 15, g = lane >> 4;
#pragma unroll
    for (int i = 0; i < 2; ++i) {
        int nt = wave + 4 * i;
        if (nt < 6) {
#pragma unroll
            for (int i2 = 0; i2 < 4; ++i2) {
                s_w[(g * 4 + i2) * 96 + nt * 16 + r] = acc0[i][i2];
                s_w[(16 + g * 4 + i2) * 96 + nt * 16 + r] = acc1[i][i2];
            }
        }
    }
}

// ---------------------------------------------------------------- K1: lat0 -> persist lat0h + w0h + scatter round 0
__global__ __launch_bounds__(256) void k1_lat_scatter0(
    const float* __restrict__ nodeinv, const float* __restrict__ edgeinv,
    const float* __restrict__ elen, const float* __restrict__ edge_attr,
    const int* __restrict__ eidx, const _Float16* __restrict__ W2aT,
    const _Float16* __restrict__ W2bT, const _Float16* __restrict__ Wenv0T,
    float* __restrict__ env, _Float16* __restrict__ lat0h,
    _Float16* __restrict__ w0h, const int* __restrict__ eord) {
    __shared__ alignas(16) _Float16 Ah[EB * AST];
    __shared__ alignas(16) _Float16 AhB[EB * BST];
    __shared__ float s_cut[EB];
    __shared__ float s_sh[EB * 9];
    __shared__ int s_nid[EB];
    float* s_w = (float*)AhB;  // overlay: AhB dead after lat0
    int t = threadIdx.x;
    int e0 = blockIdx.x * EB;
    int wave = t >> 6, lane = t & 63, r = lane & 15, g = lane >> 4;
    gather_latin(nodeinv, edgeinv, elen, eidx, eord, e0, t, Ah, s_cut);
    __syncthreads();
    lat0_mfma2(W2aT, W2bT, t, Ah, AhB, s_cut);
    // persist lat0 (f16), p-indexed
    for (int i = t; i < EB * 32; i += 256) {
        int ee = i >> 5, c8 = (i & 31) * 8;
        *(f16x8*)(lat0h + (size_t)(e0 + ee) * 256 + c8) =
            *(const f16x8*)(Ah + ee * AST + c8);
    }
    // combined Wenv0 GEMM (12 n-tiles over 192 cols)
    f32x4 acc0[3], acc1[3];
    mfma_gemm2<12>(8, Ah, AST, Wenv0T, t, acc0, acc1);
#pragma unroll
    for (int i = 0; i < 3; ++i) {
        int nt = wave + 4 * i;
        if (nt < 6) {
#pragma unroll
            for (int i2 = 0; i2 < 4; ++i2) {
                w0h[(size_t)(e0 + g * 4 + i2) * 96 + nt * 16 + r] = (_Float16)acc0[i][i2];
                w0h[(size_t)(e0 + 16 + g * 4 + i2) * 96 + nt * 16 + r] = (_Float16)acc1[i][i2];
            }
        } else {
#pragma unroll
            for (int i2 = 0; i2 < 4; ++i2) {
                s_w[(g * 4 + i2) * 96 + (nt - 6) * 16 + r] = acc0[i][i2];
                s_w[(16 + g * 4 + i2) * 96 + (nt - 6) * 16 + r] = acc1[i][i2];
            }
        }
    }
    if (eord) {
        if (t < EB) s_nid[t] = eidx[eord[e0 + t]];
        for (int i = t; i < EB * 9; i += 256) {
            int el = i / 9, m = i - el * 9;
            s_sh[i] = edge_attr[(size_t)eord[e0 + el] * 9 + m] * s_cut[el];
        }
    }
    __syncthreads();
    if (eord) scatter_sorted(s_sh, s_nid, s_w, t, env);
    else      scatter_env(edge_attr, eidx, s_w, s_cut, e0, t, env);
}

// ---------------------------------------------------------------- node transform (env input)
__global__ __launch_bounds__(288) void k_node(
    const float* envin, const float* __restrict__ nodeinv,
    const float* __restrict__ Wenvlin, const float* __restrict__ Wprod,
    const float* __restrict__ Wfeat, float* featOut) {
    __shared__ float s_env[288];
    __shared__ float s_inv[64];
    __shared__ float s_mix[288];
    __shared__ float s_ew[96];
    int n = blockIdx.x;
    int t = threadIdx.x;
    s_env[t] = envin[(size_t)n * 288 + t] * (1.0f / 32.0f);
    if (t < 64) s_inv[t] = nodeinv[n * 64 + t];
    __syncthreads();
    int m = t >> 5, j = t & 31;
    int l = (m == 0) ? 0 : ((m < 4) ? 1 : 2);
    float a = 0.f;
    for (int k = 0; k < 32; ++k) a = fmaf(s_env[m * 32 + k], Wenvlin[l * 1024 + k * 32 + j], a);
    if (t < 96) {
        int c = t >> 5, jj = t & 31;
        float b = 0.f;
        for (int tt = 0; tt < 64; ++tt) b = fmaf(s_inv[tt], Wprod[c * 2048 + tt * 32 + jj], b);
        s_ew[t] = b;
    }
    s_mix[t] = a;
    __syncthreads();
    float s = s_mix[j];
    float p = s_mix[t] * (s_ew[j] + s_ew[32 + j] * s + s_ew[64 + j] * s * s);
    __syncthreads();
    s_env[t] = p;
    __syncthreads();
    float o = 0.f;
    for (int jl = 0; jl < 32; ++jl) o = fmaf(s_env[m * 32 + jl], Wfeat[l * 1024 + jl * 32 + j], o);
    featOut[(size_t)n * 288 + t] = o;
}

// ---------------------------------------------------------------- K3: load lat0h -> lat1 (overwrite) -> Wenv1 -> scatter
__global__ __launch_bounds__(256) void k3_update_scatter1(
    const float* __restrict__ elen, const float* __restrict__ edge_attr,
    const int* __restrict__ eidx, const _Float16* __restrict__ Wl1aT,
    const _Float16* __restrict__ Wl1bT, const _Float16* __restrict__ Wenv1T,
    const float* __restrict__ featN0, float* __restrict__ env,
    _Float16* __restrict__ lat01h, const int* __restrict__ eord) {
    __shared__ alignas(16) _Float16 Ah[EB * AST];
    __shared__ alignas(16) _Float16 AhB[EB * BST];
    __shared__ float s_cut[EB];
    __shared__ float s_sh[EB * 9];
    __shared__ int s_nid[EB];
    float* s_w = (float*)AhB;
    int t = threadIdx.x;
    int e0 = blockIdx.x * EB;
    int wave = t >> 6, lane = t & 63, r = lane & 15, g = lane >> 4;
    if (t < EB) {
        int e = eord ? eord[e0 + t] : (e0 + t);
        s_cut[t] = cutf(elen[e]);
    }
    for (int i = t; i < EB * 32; i += 256) {
        int ee = i >> 5, c8 = (i & 31) * 8;
        *(f16x8*)(Ah + ee * AST + c8) =
            *(const f16x8*)(lat01h + (size_t)(e0 + ee) * 256 + c8);
    }
    gather_lnorm(featN0, eidx, eord, e0, t, Ah);
    __syncthreads();
    f32x4 acc0[4], acc1[4];
    mfma_gemm2<16>(11, Ah, AST, Wl1aT, t, acc0, acc1);
#pragma unroll
    for (int i = 0; i < 4; ++i) {
        int nt = wave + 4 * i;
#pragma unroll
        for (int i2 = 0; i2 < 4; ++i2) {
            AhB[(g * 4 + i2) * BST + nt * 16 + r] = (_Float16)silu(acc0[i][i2]);
            AhB[(16 + g * 4 + i2) * BST + nt * 16 + r] = (_Float16)silu(acc1[i][i2]);
        }
    }
    __syncthreads();
    mfma_gemm2<16>(8, AhB, BST, Wl1bT, t, acc0, acc1);
#pragma unroll
    for (int i = 0; i < 4; ++i) {
        int nt = wave + 4 * i;
#pragma unroll
        for (int i2 = 0; i2 < 4; ++i2) {
            int ro = g * 4 + i2, col = nt * 16 + r;
            float v0 = 0.8944271909999159f * (float)Ah[ro * AST + col] +
                       0.4472135954999579f * s_cut[ro] * silu(acc0[i][i2]);
            _Float16 h0 = (_Float16)v0;
            Ah[ro * AST + col] = h0;
            lat01h[(size_t)(e0 + ro) * 256 + col] = h0;
            float v1 = 0.8944271909999159f * (float)Ah[(16 + ro) * AST + col] +
                       0.4472135954999579f * s_cut[16 + ro] * silu(acc1[i][i2]);
            _Float16 h1 = (_Float16)v1;
            Ah[(16 + ro) * AST + col] = h1;
            lat01h[(size_t)(e0 + 16 + ro) * 256 + col] = h1;
        }
    }
    __syncthreads();
    mfma_gemm2<6>(8, Ah, AST, Wenv1T, t, acc0, acc1);
    epi6_f32(acc0, acc1, t, s_w);
    if (eord) {
        if (t < EB) s_nid[t] = eidx[eord[e0 + t]];
        for (int i = t; i < EB * 9; i += 256) {
            int el = i / 9, m = i - el * 9;
            s_sh[i] = edge_attr[(size_t)eord[e0 + el] * 9 + m] * s_cut[el];
        }
    }
    __syncthreads();
    if (eord) scatter_sorted(s_sh, s_nid, s_w, t, env);
    else      scatter_env(edge_attr, eidx, s_w, s_cut, e0, t, env);
}

// ---------------------------------------------------------------- K5 fast v8 (R16-proven): staged B, transposed 32x32 MFMA, deferred-S
#define FEB 128
__global__ __launch_bounds__(256) void k5_fast(
    const float* __restrict__ edge_attr, const int* __restrict__ eidx,
    const _Float16* __restrict__ lat1h, const _Float16* __restrict__ w0h,
    const _Float16* __restrict__ Bfin3, const _Float16* __restrict__ Wro1T32,
    const float* __restrict__ Wro2, const float* __restrict__ featN1,
    const int* __restrict__ eord, float* __restrict__ out) {
    __shared__ alignas(16) _Float16 Bst[2][8192];   // 32 KB stage dbuf
    __shared__ alignas(16) _Float16 s_S[FEB * SST]; // 24.5 KB: S, then scal overlay
    int t = threadIdx.x;
    int e0 = blockIdx.x * FEB;
    int wave = t >> 6, lane = t & 63;
    int r31 = lane & 31, kh5 = lane >> 5;
    // ---- S gather
    for (int i = t; i < FEB * 96; i += 256) {
        int ee = i / 96, rem = i - ee * 96;
        int l = rem >> 5, kk = rem & 31;
        int off = (l == 0) ? 0 : ((l == 1) ? 1 : 4);
        int d = (l == 0) ? 1 : ((l == 1) ? 3 : 5);
        int e = eord ? eord[e0 + ee] : (e0 + ee);
        const float* f = featN1 + (size_t)eidx[e] * 288 + kk;
        float s = 0.f;
        for (int mm = off; mm < off + d; ++mm)
            s = fmaf(f[mm * 32], edge_attr[(size_t)e * 9 + mm], s);
        s_S[ee * SST + rem] = (_Float16)s;
    }
    // ---- lat1 frags (used as MFMA *B* in contraction, *A* in readout)
    f16x8 a2[16];
#pragma unroll
    for (int q = 0; q < 16; ++q)
        a2[q] = *(const f16x8*)(lat1h + (size_t)(e0 + wave * 32 + r31) * 256 +
                                q * 16 + kh5 * 8);
    // ---- prologue: stage 0, chunk-strided (lane-contiguous)
#pragma unroll
    for (int c = 0; c < 4; ++c) {
        f16x8 gc = *(const f16x8*)(Bfin3 + (size_t)(c * 256 + t) * 8);
        *(f16x8*)&Bst[0][(c * 256 + t) * 8] = gc;
    }
    __syncthreads();
    const f32x16 z16 = {0.f, 0.f, 0.f, 0.f, 0.f, 0.f, 0.f, 0.f,
                        0.f, 0.f, 0.f, 0.f, 0.f, 0.f, 0.f, 0.f};
    f32x16 acc[3];
#pragma unroll
    for (int l = 0; l < 3; ++l) acc[l] = z16;
    int cur = 0;
#pragma unroll
    for (int l = 0; l < 3; ++l) {
#pragma unroll 1
        for (int ke = 0; ke < 32; ++ke) {
            int s = l * 32 + ke;
            f16x8 g0, g1, g2, g3;
            if (s < 95) {  // issue next-stage loads early
                const _Float16* g = Bfin3 + (size_t)(s + 1) * 8192;
                g0 = *(const f16x8*)(g + (size_t)(0 * 256 + t) * 8);
                g1 = *(const f16x8*)(g + (size_t)(1 * 256 + t) * 8);
                g2 = *(const f16x8*)(g + (size_t)(2 * 256 + t) * 8);
                g3 = *(const f16x8*)(g + (size_t)(3 * 256 + t) * 8);
            }
            float sf = (float)s_S[(wave * 32 + r31) * SST + l * 32 + ke];
            f32x16 ac = z16;
#pragma unroll
            for (int q = 0; q < 16; ++q) {
                f16x8 bf = *(const f16x8*)&Bst[cur][q * 512 + lane * 8];
                // D^T: A = Wfin frag (rows=j), B = lat1 (cols=e)
                ac = __builtin_amdgcn_mfma_f32_32x32x16_f16(bf, a2[q], ac, 0, 0, 0);
            }
#pragma unroll
            for (int reg = 0; reg < 16; ++reg)
                acc[l][reg] = fmaf(sf, ac[reg], acc[l][reg]);  // deferred S (f32)
            if (s < 95) {
                *(f16x8*)&Bst[cur ^ 1][(0 * 256 + t) * 8] = g0;
                *(f16x8*)&Bst[cur ^ 1][(1 * 256 + t) * 8] = g1;
                *(f16x8*)&Bst[cur ^ 1][(2 * 256 + t) * 8] = g2;
                *(f16x8*)&Bst[cur ^ 1][(3 * 256 + t) * 8] = g3;
            }
            __syncthreads();  // single barrier per stage
            cur ^= 1;
        }
    }
    // ---- apply w0 -> scal f16 (D^T: row=j from reg, col=e per lane)
    int pe = e0 + wave * 32 + r31;  // this lane's edge (p-space)
#pragma unroll
    for (int l = 0; l < 3; ++l) {
#pragma unroll
        for (int reg = 0; reg < 16; ++reg) {
            int jrow = (reg & 3) + 8 * (reg >> 2) + 4 * kh5;  // 32x32 D layout (m74/m101)
            float w0 = (float)w0h[(size_t)pe * 96 + jrow * 3 + l];
            s_S[(wave * 32 + r31) * SST + l * 32 + jrow] = (_Float16)(acc[l][reg] * w0);
        }
    }
    __syncthreads();
    // ---- readout: 32x32 tiles, rows = edges (a2 as A), 8 col-blocks
    float v16[16];
#pragma unroll
    for (int reg = 0; reg < 16; ++reg) v16[reg] = 0.f;
#pragma unroll 1
    for (int cb = 0; cb < 8; ++cb) {
        f32x16 racc = z16;
#pragma unroll
        for (int ks2 = 0; ks2 < 22; ++ks2) {
            f16x8 af = (ks2 < 16)
                ? a2[ks2]
                : *(const f16x8*)&s_S[(wave * 32 + r31) * SST + (ks2 - 16) * 16 + kh5 * 8];
            f16x8 b = *(const f16x8*)(Wro1T32 + ((size_t)(cb * 22 + ks2) * 512 + lane * 8));
            racc = __builtin_amdgcn_mfma_f32_32x32x16_f16(af, b, racc, 0, 0, 0);
        }
        float w2 = Wro2[cb * 32 + r31];
#pragma unroll
        for (int reg = 0; reg < 16; ++reg) v16[reg] += silu(racc[reg]) * w2;
    }
#pragma unroll
    for (int off = 1; off < 32; off <<= 1)
#pragma unroll
        for (int reg = 0; reg < 16; ++reg) v16[reg] += __shfl_xor(v16[reg], off);
    if (r31 == 0) {
#pragma unroll
        for (int reg = 0; reg < 16; ++reg) {
            int row = (reg & 3) + 8 * (reg >> 2) + 4 * kh5;
            int pidx = e0 + wave * 32 + row;
            int e = eord ? eord[pidx] : pidx;
            out[e] = v16[reg];
        }
    }
}

// ----------------------------------------------------------------
extern "C" void kernel_launch(void* const* d_in, const int* in_sizes, int n_in,
                              void* d_out, int out_size, void* d_ws, size_t ws_size,
                              hipStream_t stream) {
    (void)in_sizes; (void)n_in; (void)out_size;
    const float* edge_attr = (const float*)d_in[0];
    const float* edge_len  = (const float*)d_in[1];
    const float* edge_inv  = (const float*)d_in[2];
    const float* node_inv  = (const float*)d_in[3];
    const float* W2a     = (const float*)d_in[4];
    const float* W2b     = (const float*)d_in[5];
    const float* Wl1a    = (const float*)d_in[6];
    const float* Wl1b    = (const float*)d_in[7];
    const float* Wenv0   = (const float*)d_in[8];
    const float* Wenv1   = (const float*)d_in[9];
    const float* Wenvlin = (const float*)d_in[10];
    const float* Wprod   = (const float*)d_in[11];
    const float* Wfeat   = (const float*)d_in[12];
    const float* Wfinlat = (const float*)d_in[13];
    const float* Wro1    = (const float*)d_in[14];
    const float* Wro2    = (const float*)d_in[15];
    const int* eidx      = (const int*)d_in[16];
    float* out = (float*)d_out;

    _Float16* p = (_Float16*)d_ws;
    _Float16* Bfin3   = p; p += 786432;
    _Float16* W2aT    = p; p += 40960;
    _Float16* W2bT    = p; p += 65536;
    _Float16* Wenv0T  = p; p += 49152;   // NT=12 combined (cols 0..191)
    _Float16* Wenv1T  = p; p += 24576;
    _Float16* Wl1aT   = p; p += 90112;
    _Float16* Wl1bT   = p; p += 65536;
    _Float16* Wro1T32 = p; p += 90112;
    float* env    = (float*)p;
    float* featN0 = env + (size_t)NNODES * 288;
    char* after = (char*)(featN0 + (size_t)NNODES * 288);
    size_t need_base = (size_t)(after - (char*)d_ws);
    if (ws_size < need_base) return;
    _Float16* lat01h = (_Float16*)after;                      // NE*256 f16 (lat0 then lat1)
    _Float16* w0h    = lat01h + (size_t)NE * 256;             // NE*96 f16
    size_t need = need_base + (size_t)NE * (256 + 96) * sizeof(_Float16);
    if (ws_size < need) return;  // proven to fit since R7
    int* eord   = (int*)((char*)d_ws + need);                 // NE ints
    int* seg    = eord + NE;                                  // NNODES+1
    int* cursor = seg + NNODES + 1;                           // NNODES
    size_t need_sorted = need + (size_t)(NE + 2 * NNODES + 1) * sizeof(int);
    bool sorted = (ws_size >= need_sorted);
    const int* eordk = sorted ? eord : nullptr;

    const int ENV_N = NNODES * 288;
    k_packfin3<<<3072, 256, 0, stream>>>(Wfinlat, Bfin3);
    k_packf<<<160, 256, 0, stream>>>(W2a, W2aT, 136, 5, 16, 256, 0);
    k_packf<<<256, 256, 0, stream>>>(W2b, W2bT, 256, 8, 16, 256, 0);
    k_packf<<<192, 256, 0, stream>>>(Wenv0, Wenv0T, 256, 8, 12, 192, 0);
    k_packf<<<96, 256, 0, stream>>>(Wenv1, Wenv1T, 256, 8, 6, 96, 0);
    k_packf<<<352, 256, 0, stream>>>(Wl1a, Wl1aT, 352, 11, 16, 256, 0);
    k_packf<<<256, 256, 0, stream>>>(Wl1b, Wl1bT, 256, 8, 16, 256, 0);
    k_packro5<<<352, 256, 0, stream>>>(Wro1, Wro1T32);

    if (sorted) {
        k_zero<<<(NNODES + 255) / 256, 256, 0, stream>>>((float*)cursor, NNODES);
        k_hist<<<NE / 256, 256, 0, stream>>>(eidx, cursor);   // cursor = counts
        k_scan<<<1, 256, 0, stream>>>(cursor, seg, cursor);   // seg + cursor (aliased, fixed)
        k_place<<<NE / 256, 256, 0, stream>>>(eidx, cursor, eord);
    }

    k_zero<<<(ENV_N + 255) / 256, 256, 0, stream>>>(env, ENV_N);
    k1_lat_scatter0<<<NBLK, 256, 0, stream>>>(node_inv, edge_inv, edge_len, edge_attr,
                                              eidx, W2aT, W2bT, Wenv0T, env, lat01h, w0h,
                                              eordk);
    k_node<<<NNODES, 288, 0, stream>>>(env, node_inv, Wenvlin, Wprod, Wfeat, featN0);
    k_zero<<<(ENV_N + 255) / 256, 256, 0, stream>>>(env, ENV_N);
    k3_update_scatter1<<<NBLK, 256, 0, stream>>>(edge_len, edge_attr, eidx,
                                                 Wl1aT, Wl1bT, Wenv1T, featN0, env, lat01h,
                                                 eordk);
    k_node<<<NNODES, 288, 0, stream>>>(env, node_inv, Wenvlin + 3072, Wprod + 6144,
                                       Wfeat + 3072, env);  // in-place: env1 -> featN1
    k5_fast<<<NE / FEB, 256, 0, stream>>>(edge_attr, eidx, lat01h, w0h, Bfin3, Wro1T32,
                                          Wro2, env, eordk, out);
}

// Round 19
// 2690.950 us; speedup vs baseline: 1.2265x; 1.0015x over previous
//
#include <hip/hip_runtime.h>
#include <math.h>

#define NE 320000
#define NNODES 10000
#define EB 32
#define NBLK (NE / EB)
#define AST 360   // Ah stride (f16 elems)
#define BST 264   // AhB stride (f16 elems)
#define SST 98    // padded S/scal stride (f16)

typedef _Float16 f16x8 __attribute__((ext_vector_type(8)));
typedef float f32x4 __attribute__((ext_vector_type(4)));
typedef float f32x16 __attribute__((ext_vector_type(16)));

__device__ __forceinline__ float silu(float x) { return x / (1.0f + __expf(-x)); }
__device__ __forceinline__ float cutf(float len) {
    float x = len * (1.0f / 6.0f);
    float x2 = x * x, x6 = x2 * x2 * x2;
    float f = 1.0f - 28.0f * x6 + 48.0f * x6 * x - 21.0f * x6 * x2;
    return (x < 1.0f) ? f : 0.0f;
}

// ---------------------------------------------------------------- zero
__global__ __launch_bounds__(256) void k_zero(float* __restrict__ p, int n) {
    int i = blockIdx.x * 256 + threadIdx.x;
    if (i < n) p[i] = 0.f;
}

// ---------------------------------------------------------------- sort prep
__global__ __launch_bounds__(256) void k_hist(const int* __restrict__ eidx,
                                              int* __restrict__ cnt) {
    int e = blockIdx.x * 256 + threadIdx.x;
    if (e < NE) atomicAdd(&cnt[eidx[e]], 1);
}

__global__ __launch_bounds__(256) void k_scan(const int* __restrict__ cnt,
                                              int* __restrict__ seg,
                                              int* __restrict__ cursor) {
    __shared__ int part[256];
    __shared__ int base[256];
    int t = threadIdx.x;
    int start = t * 40;
    int s = 0;
    for (int i = 0; i < 40; ++i) {
        int idx = start + i;
        if (idx < NNODES) s += cnt[idx];
    }
    part[t] = s;
    __syncthreads();
    if (t == 0) {
        int run = 0;
        for (int i = 0; i < 256; ++i) { base[i] = run; run += part[i]; }
    }
    __syncthreads();
    int run = base[t];
    for (int i = 0; i < 40; ++i) {
        int idx = start + i;
        if (idx < NNODES) {
            int c = cnt[idx];       // read BEFORE overwriting (cnt may alias cursor)
            seg[idx] = run;
            cursor[idx] = run;
            run += c;
        }
    }
    if (t == 0) seg[NNODES] = NE;
}

__global__ __launch_bounds__(256) void k_place(const int* __restrict__ eidx,
                                               int* __restrict__ cursor,
                                               int* __restrict__ eord) {
    int e = blockIdx.x * 256 + threadIdx.x;
    if (e < NE) {
        int p = atomicAdd(&cursor[eidx[e]], 1);
        eord[p] = e;
    }
}

// ---------------------------------------------------------------- fragment-major pack for MLP weights (16x16 path)
__global__ __launch_bounds__(256) void k_packf(const float* __restrict__ src,
                                               _Float16* __restrict__ dst,
                                               int K, int KS, int NT, int stride,
                                               int colOff) {
    int i = blockIdx.x * 256 + threadIdx.x;
    if (i >= NT * KS * 512) return;
    int j = i & 7, lane = (i >> 3) & 63;
    int blk = i >> 9;
    int ks = blk % KS, nt = blk / KS;
    int k = ks * 32 + (lane >> 4) * 8 + j;
    int n = colOff + nt * 16 + (lane & 15);
    dst[i] = (k < K) ? (_Float16)src[(size_t)k * stride + n] : (_Float16)0.f;
}

// ---------------------------------------------------------------- stage-major pack of Wfinlat (32x32 pipeline, R9-proven)
__global__ __launch_bounds__(256) void k_packfin3(const float* __restrict__ W,
                                                  _Float16* __restrict__ dst) {
    int i = blockIdx.x * 256 + threadIdx.x;  // < 786432
    int j = i & 7, lane = (i >> 3) & 63, q = (i >> 9) & 15, s = i >> 13;
    int l = s >> 5, ke = s & 31;
    int c = q * 16 + (lane >> 5) * 8 + j;
    int n = l * 1024 + ke * 32 + (lane & 31);
    dst[i] = (_Float16)W[(size_t)c * 3072 + n];
}

// ---------------------------------------------------------------- 32x32x16 pack of Wro1 (readout B)
__global__ __launch_bounds__(256) void k_packro5(const float* __restrict__ W,
                                                 _Float16* __restrict__ dst) {
    int i = blockIdx.x * 256 + threadIdx.x;  // < 90112
    if (i >= 90112) return;
    int j = i & 7, lane = (i >> 3) & 63, u = i >> 9;
    int cb = u / 22, ks2 = u - cb * 22;
    int k = ks2 * 16 + (lane >> 5) * 8 + j;
    int n = cb * 32 + (lane & 31);
    dst[i] = (_Float16)W[(size_t)k * 256 + n];
}

// ---------------------------------------------------------------- MFMA GEMM, 32 edges (2 m-tiles), frag-major B
template <int NT>
__device__ __forceinline__ void mfma_gemm2(int ksteps, const _Float16* Ah, int astride,
                                           const _Float16* __restrict__ Wt, int t,
                                           f32x4* acc0, f32x4* acc1) {
    int wave = t >> 6, lane = t & 63, r = lane & 15, g = lane >> 4;
    const int TPW = (NT + 3) / 4;
#pragma unroll
    for (int i = 0; i < TPW; ++i) {
        acc0[i] = (f32x4){0.f, 0.f, 0.f, 0.f};
        acc1[i] = (f32x4){0.f, 0.f, 0.f, 0.f};
    }
    for (int ks = 0; ks < ksteps; ++ks) {
        f16x8 a0 = *(const f16x8*)(Ah + r * astride + ks * 32 + g * 8);
        f16x8 a1 = *(const f16x8*)(Ah + (16 + r) * astride + ks * 32 + g * 8);
#pragma unroll
        for (int i = 0; i < TPW; ++i) {
            int nt = wave + 4 * i;
            if (nt < NT) {
                f16x8 b = *(const f16x8*)(Wt + ((size_t)(nt * ksteps + ks) * 64 + lane) * 8);
                acc0[i] = __builtin_amdgcn_mfma_f32_16x16x32_f16(a0, b, acc0[i], 0, 0, 0);
                acc1[i] = __builtin_amdgcn_mfma_f32_16x16x32_f16(a1, b, acc1[i], 0, 0, 0);
            }
        }
    }
}

// gather lat_in -> Ah cols 0..159 (f16), compute s_cut (p-space when eord)
__device__ __forceinline__ void gather_latin(
    const float* __restrict__ nodeinv, const float* __restrict__ edgeinv,
    const float* __restrict__ elen, const int* __restrict__ eidx,
    const int* __restrict__ eord, int e0, int t, _Float16* Ah, float* s_cut) {
    if (t < EB) {
        int e = eord ? eord[e0 + t] : (e0 + t);
        s_cut[t] = cutf(elen[e]);
    }
    for (int i = t; i < EB * 160; i += 256) {
        int ee = i / 160, k = i - ee * 160;
        int e = eord ? eord[e0 + ee] : (e0 + ee);
        float v;
        if (k < 64)       v = nodeinv[eidx[e] * 64 + k];
        else if (k < 128) v = nodeinv[eidx[NE + e] * 64 + (k - 64)];
        else if (k < 136) v = edgeinv[(size_t)e * 8 + (k - 128)];
        else              v = 0.f;
        Ah[ee * AST + k] = (_Float16)v;
    }
}

// lat0 (2 GEMMs) -> Ah cols 0..255 f16
__device__ __forceinline__ void lat0_mfma2(const _Float16* __restrict__ W2aT,
                                           const _Float16* __restrict__ W2bT,
                                           int t, _Float16* Ah, _Float16* AhB,
                                           const float* s_cut) {
    int wave = t >> 6, lane = t & 63, r = lane & 15, g = lane >> 4;
    f32x4 acc0[4], acc1[4];
    mfma_gemm2<16>(5, Ah, AST, W2aT, t, acc0, acc1);
#pragma unroll
    for (int i = 0; i < 4; ++i) {
        int nt = wave + 4 * i;
#pragma unroll
        for (int i2 = 0; i2 < 4; ++i2) {
            AhB[(g * 4 + i2) * BST + nt * 16 + r] = (_Float16)silu(acc0[i][i2]);
            AhB[(16 + g * 4 + i2) * BST + nt * 16 + r] = (_Float16)silu(acc1[i][i2]);
        }
    }
    __syncthreads();
    mfma_gemm2<16>(8, AhB, BST, W2bT, t, acc0, acc1);
#pragma unroll
    for (int i = 0; i < 4; ++i) {
        int nt = wave + 4 * i;
#pragma unroll
        for (int i2 = 0; i2 < 4; ++i2) {
            int ro = g * 4 + i2, col = nt * 16 + r;
            Ah[ro * AST + col] = (_Float16)(s_cut[ro] * silu(acc0[i][i2]));
            Ah[(16 + ro) * AST + col] = (_Float16)(s_cut[16 + ro] * silu(acc1[i][i2]));
        }
    }
    __syncthreads();
}

// lnorm(featN[center]) -> Ah cols 256..351 f16
__device__ __forceinline__ void gather_lnorm(const float* __restrict__ featN,
                                             const int* __restrict__ eidx,
                                             const int* __restrict__ eord,
                                             int e0, int t, _Float16* Ah) {
    for (int i = t; i < EB * 96; i += 256) {
        int ee = i / 96, rem = i - ee * 96;
        int l = rem >> 5, kk = rem & 31;
        int off = (l == 0) ? 0 : ((l == 1) ? 1 : 4);
        int d = (l == 0) ? 1 : ((l == 1) ? 3 : 5);
        int e = eord ? eord[e0 + ee] : (e0 + ee);
        const float* f = featN + (size_t)eidx[e] * 288 + kk;
        float s = 1e-8f;
        for (int mm = off; mm < off + d; ++mm) { float x = f[mm * 32]; s = fmaf(x, x, s); }
        Ah[ee * AST + 256 + rem] = (_Float16)sqrtf(s);
    }
}

// unsorted atomic scatter into env (fallback)
__device__ __forceinline__ void scatter_env(const float* __restrict__ edge_attr,
                                            const int* __restrict__ eidx,
                                            const float* s_w, const float* s_cut,
                                            int e0, int t, float* __restrict__ env) {
    for (int i = t; i < EB * 32; i += 256) {
        int el = i >> 5, k = i & 31;
        int e = e0 + el;
        float cw = s_cut[el];
        int n = eidx[e];
        float w0 = s_w[el * 96 + k * 3 + 0] * cw;
        float w1 = s_w[el * 96 + k * 3 + 1] * cw;
        float w2 = s_w[el * 96 + k * 3 + 2] * cw;
        float* dst = env + (size_t)n * 288 + k;
#pragma unroll
        for (int m = 0; m < 9; ++m) {
            float w = (m == 0) ? w0 : ((m < 4) ? w1 : w2);
            atomicAdd(dst + m * 32, edge_attr[(size_t)e * 9 + m] * w);
        }
    }
}

// sorted segmented-flush scatter: s_sh = sh*cut, s_nid nondecreasing
__device__ __forceinline__ void scatter_sorted(const float* s_sh, const int* s_nid,
                                               const float* s_w, int t,
                                               float* __restrict__ env) {
    for (int pp = t; pp < 288; pp += 256) {
        int m = pp >> 5, k = pp & 31;
        int l = (m == 0) ? 0 : ((m < 4) ? 1 : 2);
        float run = 0.f;
        int nprev = s_nid[0];
        for (int el = 0; el < EB; ++el) {
            int nid = s_nid[el];
            if (nid != nprev) {
                atomicAdd(&env[(size_t)nprev * 288 + m * 32 + k], run);
                run = 0.f;
                nprev = nid;
            }
            run = fmaf(s_sh[el * 9 + m], s_w[el * 96 + k * 3 + l], run);
        }
        atomicAdd(&env[(size_t)nprev * 288 + m * 32 + k], run);
    }
}

// NT=6 epilogue -> s_w (f32)
__device__ __forceinline__ void epi6_f32(const f32x4* acc0, const f32x4* acc1, int t,
                                         float* s_w) {
    int wave = t >> 6, lane = t & 63, r = lane & 15, g = lane >> 4;
#pragma unroll
    for (int i = 0; i < 2; ++i) {
        int nt = wave + 4 * i;
        if (nt < 6) {
#pragma unroll
            for (int i2 = 0; i2 < 4; ++i2) {
                s_w[(g * 4 + i2) * 96 + nt * 16 + r] = acc0[i][i2];
                s_w[(16 + g * 4 + i2) * 96 + nt * 16 + r] = acc1[i][i2];
            }
        }
    }
}

// ---------------------------------------------------------------- K1: lat0 -> persist lat0h + w0h + scatter round 0
__global__ __launch_bounds__(256) void k1_lat_scatter0(
    const float* __restrict__ nodeinv, const float* __restrict__ edgeinv,
    const float* __restrict__ elen, const float* __restrict__ edge_attr,
    const int* __restrict__ eidx, const _Float16* __restrict__ W2aT,
    const _Float16* __restrict__ W2bT, const _Float16* __restrict__ Wenv0T,
    float* __restrict__ env, _Float16* __restrict__ lat0h,
    _Float16* __restrict__ w0h, const int* __restrict__ eord) {
    __shared__ alignas(16) _Float16 Ah[EB * AST];
    __shared__ alignas(16) _Float16 AhB[EB * BST];
    __shared__ float s_cut[EB];
    __shared__ float s_sh[EB * 9];
    __shared__ int s_nid[EB];
    float* s_w = (float*)AhB;  // overlay: AhB dead after lat0
    int t = threadIdx.x;
    int e0 = blockIdx.x * EB;
    int wave = t >> 6, lane = t & 63, r = lane & 15, g = lane >> 4;
    gather_latin(nodeinv, edgeinv, elen, eidx, eord, e0, t, Ah, s_cut);
    __syncthreads();
    lat0_mfma2(W2aT, W2bT, t, Ah, AhB, s_cut);
    // persist lat0 (f16), p-indexed
    for (int i = t; i < EB * 32; i += 256) {
        int ee = i >> 5, c8 = (i & 31) * 8;
        *(f16x8*)(lat0h + (size_t)(e0 + ee) * 256 + c8) =
            *(const f16x8*)(Ah + ee * AST + c8);
    }
    // combined Wenv0 GEMM (12 n-tiles over 192 cols)
    f32x4 acc0[3], acc1[3];
    mfma_gemm2<12>(8, Ah, AST, Wenv0T, t, acc0, acc1);
#pragma unroll
    for (int i = 0; i < 3; ++i) {
        int nt = wave + 4 * i;
        if (nt < 6) {
#pragma unroll
            for (int i2 = 0; i2 < 4; ++i2) {
                w0h[(size_t)(e0 + g * 4 + i2) * 96 + nt * 16 + r] = (_Float16)acc0[i][i2];
                w0h[(size_t)(e0 + 16 + g * 4 + i2) * 96 + nt * 16 + r] = (_Float16)acc1[i][i2];
            }
        } else {
#pragma unroll
            for (int i2 = 0; i2 < 4; ++i2) {
                s_w[(g * 4 + i2) * 96 + (nt - 6) * 16 + r] = acc0[i][i2];
                s_w[(16 + g * 4 + i2) * 96 + (nt - 6) * 16 + r] = acc1[i][i2];
            }
        }
    }
    if (eord) {
        if (t < EB) s_nid[t] = eidx[eord[e0 + t]];
        for (int i = t; i < EB * 9; i += 256) {
            int el = i / 9, m = i - el * 9;
            s_sh[i] = edge_attr[(size_t)eord[e0 + el] * 9 + m] * s_cut[el];
        }
    }
    __syncthreads();
    if (eord) scatter_sorted(s_sh, s_nid, s_w, t, env);
    else      scatter_env(edge_attr, eidx, s_w, s_cut, e0, t, env);
}

// ---------------------------------------------------------------- node transform (env input)
__global__ __launch_bounds__(288) void k_node(
    const float* envin, const float* __restrict__ nodeinv,
    const float* __restrict__ Wenvlin, const float* __restrict__ Wprod,
    const float* __restrict__ Wfeat, float* featOut) {
    __shared__ float s_env[288];
    __shared__ float s_inv[64];
    __shared__ float s_mix[288];
    __shared__ float s_ew[96];
    int n = blockIdx.x;
    int t = threadIdx.x;
    s_env[t] = envin[(size_t)n * 288 + t] * (1.0f / 32.0f);
    if (t < 64) s_inv[t] = nodeinv[n * 64 + t];
    __syncthreads();
    int m = t >> 5, j = t & 31;
    int l = (m == 0) ? 0 : ((m < 4) ? 1 : 2);
    float a = 0.f;
    for (int k = 0; k < 32; ++k) a = fmaf(s_env[m * 32 + k], Wenvlin[l * 1024 + k * 32 + j], a);
    if (t < 96) {
        int c = t >> 5, jj = t & 31;
        float b = 0.f;
        for (int tt = 0; tt < 64; ++tt) b = fmaf(s_inv[tt], Wprod[c * 2048 + tt * 32 + jj], b);
        s_ew[t] = b;
    }
    s_mix[t] = a;
    __syncthreads();
    float s = s_mix[j];
    float p = s_mix[t] * (s_ew[j] + s_ew[32 + j] * s + s_ew[64 + j] * s * s);
    __syncthreads();
    s_env[t] = p;
    __syncthreads();
    float o = 0.f;
    for (int jl = 0; jl < 32; ++jl) o = fmaf(s_env[m * 32 + jl], Wfeat[l * 1024 + jl * 32 + j], o);
    featOut[(size_t)n * 288 + t] = o;
}

// ---------------------------------------------------------------- K3: load lat0h -> lat1 (overwrite) -> Wenv1 -> scatter
__global__ __launch_bounds__(256) void k3_update_scatter1(
    const float* __restrict__ elen, const float* __restrict__ edge_attr,
    const int* __restrict__ eidx, const _Float16* __restrict__ Wl1aT,
    const _Float16* __restrict__ Wl1bT, const _Float16* __restrict__ Wenv1T,
    const float* __restrict__ featN0, float* __restrict__ env,
    _Float16* __restrict__ lat01h, const int* __restrict__ eord) {
    __shared__ alignas(16) _Float16 Ah[EB * AST];
    __shared__ alignas(16) _Float16 AhB[EB * BST];
    __shared__ float s_cut[EB];
    __shared__ float s_sh[EB * 9];
    __shared__ int s_nid[EB];
    float* s_w = (float*)AhB;
    int t = threadIdx.x;
    int e0 = blockIdx.x * EB;
    int wave = t >> 6, lane = t & 63, r = lane & 15, g = lane >> 4;
    if (t < EB) {
        int e = eord ? eord[e0 + t] : (e0 + t);
        s_cut[t] = cutf(elen[e]);
    }
    for (int i = t; i < EB * 32; i += 256) {
        int ee = i >> 5, c8 = (i & 31) * 8;
        *(f16x8*)(Ah + ee * AST + c8) =
            *(const f16x8*)(lat01h + (size_t)(e0 + ee) * 256 + c8);
    }
    gather_lnorm(featN0, eidx, eord, e0, t, Ah);
    __syncthreads();
    f32x4 acc0[4], acc1[4];
    mfma_gemm2<16>(11, Ah, AST, Wl1aT, t, acc0, acc1);
#pragma unroll
    for (int i = 0; i < 4; ++i) {
        int nt = wave + 4 * i;
#pragma unroll
        for (int i2 = 0; i2 < 4; ++i2) {
            AhB[(g * 4 + i2) * BST + nt * 16 + r] = (_Float16)silu(acc0[i][i2]);
            AhB[(16 + g * 4 + i2) * BST + nt * 16 + r] = (_Float16)silu(acc1[i][i2]);
        }
    }
    __syncthreads();
    mfma_gemm2<16>(8, AhB, BST, Wl1bT, t, acc0, acc1);
#pragma unroll
    for (int i = 0; i < 4; ++i) {
        int nt = wave + 4 * i;
#pragma unroll
        for (int i2 = 0; i2 < 4; ++i2) {
            int ro = g * 4 + i2, col = nt * 16 + r;
            float v0 = 0.8944271909999159f * (float)Ah[ro * AST + col] +
                       0.4472135954999579f * s_cut[ro] * silu(acc0[i][i2]);
            _Float16 h0 = (_Float16)v0;
            Ah[ro * AST + col] = h0;
            lat01h[(size_t)(e0 + ro) * 256 + col] = h0;
            float v1 = 0.8944271909999159f * (float)Ah[(16 + ro) * AST + col] +
                       0.4472135954999579f * s_cut[16 + ro] * silu(acc1[i][i2]);
            _Float16 h1 = (_Float16)v1;
            Ah[(16 + ro) * AST + col] = h1;
            lat01h[(size_t)(e0 + 16 + ro) * 256 + col] = h1;
        }
    }
    __syncthreads();
    mfma_gemm2<6>(8, Ah, AST, Wenv1T, t, acc0, acc1);
    epi6_f32(acc0, acc1, t, s_w);
    if (eord) {
        if (t < EB) s_nid[t] = eidx[eord[e0 + t]];
        for (int i = t; i < EB * 9; i += 256) {
            int el = i / 9, m = i - el * 9;
            s_sh[i] = edge_attr[(size_t)eord[e0 + el] * 9 + m] * s_cut[el];
        }
    }
    __syncthreads();
    if (eord) scatter_sorted(s_sh, s_nid, s_w, t, env);
    else      scatter_env(edge_attr, eidx, s_w, s_cut, e0, t, env);
}

// ---------------------------------------------------------------- K5 fast v10: single-buffer staging (2 barriers), 3 blocks/CU
#define FEB 128
__global__ __launch_bounds__(256) void k5_fast(
    const float* __restrict__ edge_attr, const int* __restrict__ eidx,
    const _Float16* __restrict__ lat1h, const _Float16* __restrict__ w0h,
    const _Float16* __restrict__ Bfin3, const _Float16* __restrict__ Wro1T32,
    const float* __restrict__ Wro2, const float* __restrict__ featN1,
    const int* __restrict__ eord, float* __restrict__ out) {
    __shared__ alignas(16) _Float16 Bst[8192];      // 16 KB single stage buffer
    __shared__ alignas(16) _Float16 s_S[FEB * SST]; // 24.5 KB: S, then scal overlay
    int t = threadIdx.x;
    int e0 = blockIdx.x * FEB;
    int wave = t >> 6, lane = t & 63;
    int r31 = lane & 31, kh5 = lane >> 5;
    // ---- S gather
    for (int i = t; i < FEB * 96; i += 256) {
        int ee = i / 96, rem = i - ee * 96;
        int l = rem >> 5, kk = rem & 31;
        int off = (l == 0) ? 0 : ((l == 1) ? 1 : 4);
        int d = (l == 0) ? 1 : ((l == 1) ? 3 : 5);
        int e = eord ? eord[e0 + ee] : (e0 + ee);
        const float* f = featN1 + (size_t)eidx[e] * 288 + kk;
        float s = 0.f;
        for (int mm = off; mm < off + d; ++mm)
            s = fmaf(f[mm * 32], edge_attr[(size_t)e * 9 + mm], s);
        s_S[ee * SST + rem] = (_Float16)s;
    }
    // ---- lat1 frags (used as MFMA *B* in contraction, *A* in readout)
    f16x8 a2[16];
#pragma unroll
    for (int q = 0; q < 16; ++q)
        a2[q] = *(const f16x8*)(lat1h + (size_t)(e0 + wave * 32 + r31) * 256 +
                                q * 16 + kh5 * 8);
    // ---- prologue: stage 0, chunk-strided (lane-contiguous)
#pragma unroll
    for (int c = 0; c < 4; ++c) {
        f16x8 gc = *(const f16x8*)(Bfin3 + (size_t)(c * 256 + t) * 8);
        *(f16x8*)&Bst[(c * 256 + t) * 8] = gc;
    }
    __syncthreads();
    const f32x16 z16 = {0.f, 0.f, 0.f, 0.f, 0.f, 0.f, 0.f, 0.f,
                        0.f, 0.f, 0.f, 0.f, 0.f, 0.f, 0.f, 0.f};
    f32x16 acc[3];
#pragma unroll
    for (int l = 0; l < 3; ++l) acc[l] = z16;
#pragma unroll
    for (int l = 0; l < 3; ++l) {
#pragma unroll 1
        for (int ke = 0; ke < 32; ++ke) {
            int s = l * 32 + ke;
            f16x8 g0, g1, g2, g3;
            if (s < 95) {  // issue next-stage loads early
                const _Float16* g = Bfin3 + (size_t)(s + 1) * 8192;
                g0 = *(const f16x8*)(g + (size_t)(0 * 256 + t) * 8);
                g1 = *(const f16x8*)(g + (size_t)(1 * 256 + t) * 8);
                g2 = *(const f16x8*)(g + (size_t)(2 * 256 + t) * 8);
                g3 = *(const f16x8*)(g + (size_t)(3 * 256 + t) * 8);
            }
            float sf = (float)s_S[(wave * 32 + r31) * SST + l * 32 + ke];
            f32x16 ac = z16;
#pragma unroll
            for (int q = 0; q < 16; ++q) {
                f16x8 bf = *(const f16x8*)&Bst[q * 512 + lane * 8];
                // D^T: A = Wfin frag (rows=j), B = lat1 (cols=e)
                ac = __builtin_amdgcn_mfma_f32_32x32x16_f16(bf, a2[q], ac, 0, 0, 0);
            }
#pragma unroll
            for (int reg = 0; reg < 16; ++reg)
                acc[l][reg] = fmaf(sf, ac[reg], acc[l][reg]);  // deferred S (f32)
            __syncthreads();  // all reads of Bst done
            if (s < 95) {
                *(f16x8*)&Bst[(0 * 256 + t) * 8] = g0;
                *(f16x8*)&Bst[(1 * 256 + t) * 8] = g1;
                *(f16x8*)&Bst[(2 * 256 + t) * 8] = g2;
                *(f16x8*)&Bst[(3 * 256 + t) * 8] = g3;
            }
            __syncthreads();  // next stage visible
        }
    }
    // ---- apply w0 -> scal f16 (D^T: row=j from reg, col=e per lane)
    int pe = e0 + wave * 32 + r31;  // this lane's edge (p-space)
#pragma unroll
    for (int l = 0; l < 3; ++l) {
#pragma unroll
        for (int reg = 0; reg < 16; ++reg) {
            int jrow = (reg & 3) + 8 * (reg >> 2) + 4 * kh5;  // 32x32 D layout (m74/m101)
            float w0 = (float)w0h[(size_t)pe * 96 + jrow * 3 + l];
            s_S[(wave * 32 + r31) * SST + l * 32 + jrow] = (_Float16)(acc[l][reg] * w0);
        }
    }
    __syncthreads();
    // ---- readout: 32x32 tiles, rows = edges (a2 as A), 8 col-blocks
    float v16[16];
#pragma unroll
    for (int reg = 0; reg < 16; ++reg) v16[reg] = 0.f;
#pragma unroll 1
    for (int cb = 0; cb < 8; ++cb) {
        f32x16 racc = z16;
#pragma unroll
        for (int ks2 = 0; ks2 < 22; ++ks2) {
            f16x8 af = (ks2 < 16)
                ? a2[ks2]
                : *(const f16x8*)&s_S[(wave * 32 + r31) * SST + (ks2 - 16) * 16 + kh5 * 8];
            f16x8 b = *(const f16x8*)(Wro1T32 + ((size_t)(cb * 22 + ks2) * 512 + lane * 8));
            racc = __builtin_amdgcn_mfma_f32_32x32x16_f16(af, b, racc, 0, 0, 0);
        }
        float w2 = Wro2[cb * 32 + r31];
#pragma unroll
        for (int reg = 0; reg < 16; ++reg) v16[reg] += silu(racc[reg]) * w2;
    }
#pragma unroll
    for (int off = 1; off < 32; off <<= 1)
#pragma unroll
        for (int reg = 0; reg < 16; ++reg) v16[reg] += __shfl_xor(v16[reg], off);
    if (r31 == 0) {
#pragma unroll
        for (int reg = 0; reg < 16; ++reg) {
            int row = (reg & 3) + 8 * (reg >> 2) + 4 * kh5;
            int pidx = e0 + wave * 32 + row;
            int e = eord ? eord[pidx] : pidx;
            out[e] = v16[reg];
        }
    }
}

// ----------------------------------------------------------------
extern "C" void kernel_launch(void* const* d_in, const int* in_sizes, int n_in,
                              void* d_out, int out_size, void* d_ws, size_t ws_size,
                              hipStream_t stream) {
    (void)in_sizes; (void)n_in; (void)out_size;
    const float* edge_attr = (const float*)d_in[0];
    const float* edge_len  = (const float*)d_in[1];
    const float* edge_inv  = (const float*)d_in[2];
    const float* node_inv  = (const float*)d_in[3];
    const float* W2a     = (const float*)d_in[4];
    const float* W2b     = (const float*)d_in[5];
    const float* Wl1a    = (const float*)d_in[6];
    const float* Wl1b    = (const float*)d_in[7];
    const float* Wenv0   = (const float*)d_in[8];
    const float* Wenv1   = (const float*)d_in[9];
    const float* Wenvlin = (const float*)d_in[10];
    const float* Wprod   = (const float*)d_in[11];
    const float* Wfeat   = (const float*)d_in[12];
    const float* Wfinlat = (const float*)d_in[13];
    const float* Wro1    = (const float*)d_in[14];
    const float* Wro2    = (const float*)d_in[15];
    const int* eidx      = (const int*)d_in[16];
    float* out = (float*)d_out;

    _Float16* p = (_Float16*)d_ws;
    _Float16* Bfin3   = p; p += 786432;
    _Float16* W2aT    = p; p += 40960;
    _Float16* W2bT    = p; p += 65536;
    _Float16* Wenv0T  = p; p += 49152;   // NT=12 combined (cols 0..191)
    _Float16* Wenv1T  = p; p += 24576;
    _Float16* Wl1aT   = p; p += 90112;
    _Float16* Wl1bT   = p; p += 65536;
    _Float16* Wro1T32 = p; p += 90112;
    float* env    = (float*)p;
    float* featN0 = env + (size_t)NNODES * 288;
    char* after = (char*)(featN0 + (size_t)NNODES * 288);
    size_t need_base = (size_t)(after - (char*)d_ws);
    if (ws_size < need_base) return;
    _Float16* lat01h = (_Float16*)after;                      // NE*256 f16 (lat0 then lat1)
    _Float16* w0h    = lat01h + (size_t)NE * 256;             // NE*96 f16
    size_t need = need_base + (size_t)NE * (256 + 96) * sizeof(_Float16);
    if (ws_size < need) return;  // proven to fit since R7
    int* eord   = (int*)((char*)d_ws + need);                 // NE ints
    int* seg    = eord + NE;                                  // NNODES+1
    int* cursor = seg + NNODES + 1;                           // NNODES
    size_t need_sorted = need + (size_t)(NE + 2 * NNODES + 1) * sizeof(int);
    bool sorted = (ws_size >= need_sorted);
    const int* eordk = sorted ? eord : nullptr;

    const int ENV_N = NNODES * 288;
    k_packfin3<<<3072, 256, 0, stream>>>(Wfinlat, Bfin3);
    k_packf<<<160, 256, 0, stream>>>(W2a, W2aT, 136, 5, 16, 256, 0);
    k_packf<<<256, 256, 0, stream>>>(W2b, W2bT, 256, 8, 16, 256, 0);
    k_packf<<<192, 256, 0, stream>>>(Wenv0, Wenv0T, 256, 8, 12, 192, 0);
    k_packf<<<96, 256, 0, stream>>>(Wenv1, Wenv1T, 256, 8, 6, 96, 0);
    k_packf<<<352, 256, 0, stream>>>(Wl1a, Wl1aT, 352, 11, 16, 256, 0);
    k_packf<<<256, 256, 0, stream>>>(Wl1b, Wl1bT, 256, 8, 16, 256, 0);
    k_packro5<<<352, 256, 0, stream>>>(Wro1, Wro1T32);

    if (sorted) {
        k_zero<<<(NNODES + 255) / 256, 256, 0, stream>>>((float*)cursor, NNODES);
        k_hist<<<NE / 256, 256, 0, stream>>>(eidx, cursor);   // cursor = counts
        k_scan<<<1, 256, 0, stream>>>(cursor, seg, cursor);   // seg + cursor (aliased, fixed)
        k_place<<<NE / 256, 256, 0, stream>>>(eidx, cursor, eord);
    }

    k_zero<<<(ENV_N + 255) / 256, 256, 0, stream>>>(env, ENV_N);
    k1_lat_scatter0<<<NBLK, 256, 0, stream>>>(node_inv, edge_inv, edge_len, edge_attr,
                                              eidx, W2aT, W2bT, Wenv0T, env, lat01h, w0h,
                                              eordk);
    k_node<<<NNODES, 288, 0, stream>>>(env, node_inv, Wenvlin, Wprod, Wfeat, featN0);
    k_zero<<<(ENV_N + 255) / 256, 256, 0, stream>>>(env, ENV_N);
    k3_update_scatter1<<<NBLK, 256, 0, stream>>>(edge_len, edge_attr, eidx,
                                                 Wl1aT, Wl1bT, Wenv1T, featN0, env, lat01h,
                                                 eordk);
    k_node<<<NNODES, 288, 0, stream>>>(env, node_inv, Wenvlin + 3072, Wprod + 6144,
                                       Wfeat + 3072, env);  // in-place: env1 -> featN1
    k5_fast<<<NE / FEB, 256, 0, stream>>>(edge_attr, eidx, lat01h, w0h, Bfin3, Wro1T32,
                                          Wro2, env, eordk, out);
}

// Round 20
// 2634.844 us; speedup vs baseline: 1.2526x; 1.0213x over previous
//
#include <hip/hip_runtime.h>
#include <math.h>

#define NE 320000
#define NNODES 10000
#define EB 32
#define NBLK (NE / EB)
#define AST 360   // Ah stride (f16 elems)
#define BST 264   // AhB stride (f16 elems)
#define SST 98    // padded S/scal stride (f16)

typedef _Float16 f16x8 __attribute__((ext_vector_type(8)));
typedef float f32x4 __attribute__((ext_vector_type(4)));
typedef float f32x16 __attribute__((ext_vector_type(16)));

__device__ __forceinline__ float silu(float x) { return x / (1.0f + __expf(-x)); }
__device__ __forceinline__ float cutf(float len) {
    float x = len * (1.0f / 6.0f);
    float x2 = x * x, x6 = x2 * x2 * x2;
    float f = 1.0f - 28.0f * x6 + 48.0f * x6 * x - 21.0f * x6 * x2;
    return (x < 1.0f) ? f : 0.0f;
}

// ---------------------------------------------------------------- zero
__global__ __launch_bounds__(256) void k_zero(float* __restrict__ p, int n) {
    int i = blockIdx.x * 256 + threadIdx.x;
    if (i < n) p[i] = 0.f;
}

// ---------------------------------------------------------------- sort prep
__global__ __launch_bounds__(256) void k_hist(const int* __restrict__ eidx,
                                              int* __restrict__ cnt) {
    int e = blockIdx.x * 256 + threadIdx.x;
    if (e < NE) atomicAdd(&cnt[eidx[e]], 1);
}

__global__ __launch_bounds__(256) void k_scan(const int* __restrict__ cnt,
                                              int* __restrict__ seg,
                                              int* __restrict__ cursor) {
    __shared__ int part[256];
    __shared__ int base[256];
    int t = threadIdx.x;
    int start = t * 40;
    int s = 0;
    for (int i = 0; i < 40; ++i) {
        int idx = start + i;
        if (idx < NNODES) s += cnt[idx];
    }
    part[t] = s;
    __syncthreads();
    if (t == 0) {
        int run = 0;
        for (int i = 0; i < 256; ++i) { base[i] = run; run += part[i]; }
    }
    __syncthreads();
    int run = base[t];
    for (int i = 0; i < 40; ++i) {
        int idx = start + i;
        if (idx < NNODES) {
            int c = cnt[idx];       // read BEFORE overwriting (cnt may alias cursor)
            seg[idx] = run;
            cursor[idx] = run;
            run += c;
        }
    }
    if (t == 0) seg[NNODES] = NE;
}

__global__ __launch_bounds__(256) void k_place(const int* __restrict__ eidx,
                                               int* __restrict__ cursor,
                                               int* __restrict__ eord) {
    int e = blockIdx.x * 256 + threadIdx.x;
    if (e < NE) {
        int p = atomicAdd(&cursor[eidx[e]], 1);
        eord[p] = e;
    }
}

// ---------------------------------------------------------------- fragment-major pack for MLP weights (16x16 path)
__global__ __launch_bounds__(256) void k_packf(const float* __restrict__ src,
                                               _Float16* __restrict__ dst,
                                               int K, int KS, int NT, int stride,
                                               int colOff) {
    int i = blockIdx.x * 256 + threadIdx.x;
    if (i >= NT * KS * 512) return;
    int j = i & 7, lane = (i >> 3) & 63;
    int blk = i >> 9;
    int ks = blk % KS, nt = blk / KS;
    int k = ks * 32 + (lane >> 4) * 8 + j;
    int n = colOff + nt * 16 + (lane & 15);
    dst[i] = (k < K) ? (_Float16)src[(size_t)k * stride + n] : (_Float16)0.f;
}

// ---------------------------------------------------------------- stage-major pack of Wfinlat (32x32 pipeline, R9-proven)
__global__ __launch_bounds__(256) void k_packfin3(const float* __restrict__ W,
                                                  _Float16* __restrict__ dst) {
    int i = blockIdx.x * 256 + threadIdx.x;  // < 786432
    int j = i & 7, lane = (i >> 3) & 63, q = (i >> 9) & 15, s = i >> 13;
    int l = s >> 5, ke = s & 31;
    int c = q * 16 + (lane >> 5) * 8 + j;
    int n = l * 1024 + ke * 32 + (lane & 31);
    dst[i] = (_Float16)W[(size_t)c * 3072 + n];
}

// ---------------------------------------------------------------- 32x32x16 pack of Wro1 (readout B)
__global__ __launch_bounds__(256) void k_packro5(const float* __restrict__ W,
                                                 _Float16* __restrict__ dst) {
    int i = blockIdx.x * 256 + threadIdx.x;  // < 90112
    if (i >= 90112) return;
    int j = i & 7, lane = (i >> 3) & 63, u = i >> 9;
    int cb = u / 22, ks2 = u - cb * 22;
    int k = ks2 * 16 + (lane >> 5) * 8 + j;
    int n = cb * 32 + (lane & 31);
    dst[i] = (_Float16)W[(size_t)k * 256 + n];
}

// ---------------------------------------------------------------- MFMA GEMM, 32 edges (2 m-tiles), frag-major B
template <int NT>
__device__ __forceinline__ void mfma_gemm2(int ksteps, const _Float16* Ah, int astride,
                                           const _Float16* __restrict__ Wt, int t,
                                           f32x4* acc0, f32x4* acc1) {
    int wave = t >> 6, lane = t & 63, r = lane & 15, g = lane >> 4;
    const int TPW = (NT + 3) / 4;
#pragma unroll
    for (int i = 0; i < TPW; ++i) {
        acc0[i] = (f32x4){0.f, 0.f, 0.f, 0.f};
        acc1[i] = (f32x4){0.f, 0.f, 0.f, 0.f};
    }
    for (int ks = 0; ks < ksteps; ++ks) {
        f16x8 a0 = *(const f16x8*)(Ah + r * astride + ks * 32 + g * 8);
        f16x8 a1 = *(const f16x8*)(Ah + (16 + r) * astride + ks * 32 + g * 8);
#pragma unroll
        for (int i = 0; i < TPW; ++i) {
            int nt = wave + 4 * i;
            if (nt < NT) {
                f16x8 b = *(const f16x8*)(Wt + ((size_t)(nt * ksteps + ks) * 64 + lane) * 8);
                acc0[i] = __builtin_amdgcn_mfma_f32_16x16x32_f16(a0, b, acc0[i], 0, 0, 0);
                acc1[i] = __builtin_amdgcn_mfma_f32_16x16x32_f16(a1, b, acc1[i], 0, 0, 0);
            }
        }
    }
}

// gather lat_in -> Ah cols 0..159 (f16), compute s_cut (p-space when eord)
__device__ __forceinline__ void gather_latin(
    const float* __restrict__ nodeinv, const float* __restrict__ edgeinv,
    const float* __restrict__ elen, const int* __restrict__ eidx,
    const int* __restrict__ eord, int e0, int t, _Float16* Ah, float* s_cut) {
    if (t < EB) {
        int e = eord ? eord[e0 + t] : (e0 + t);
        s_cut[t] = cutf(elen[e]);
    }
    for (int i = t; i < EB * 160; i += 256) {
        int ee = i / 160, k = i - ee * 160;
        int e = eord ? eord[e0 + ee] : (e0 + ee);
        float v;
        if (k < 64)       v = nodeinv[eidx[e] * 64 + k];
        else if (k < 128) v = nodeinv[eidx[NE + e] * 64 + (k - 64)];
        else if (k < 136) v = edgeinv[(size_t)e * 8 + (k - 128)];
        else              v = 0.f;
        Ah[ee * AST + k] = (_Float16)v;
    }
}

// lat0 (2 GEMMs) -> Ah cols 0..255 f16
__device__ __forceinline__ void lat0_mfma2(const _Float16* __restrict__ W2aT,
                                           const _Float16* __restrict__ W2bT,
                                           int t, _Float16* Ah, _Float16* AhB,
                                           const float* s_cut) {
    int wave = t >> 6, lane = t & 63, r = lane & 15, g = lane >> 4;
    f32x4 acc0[4], acc1[4];
    mfma_gemm2<16>(5, Ah, AST, W2aT, t, acc0, acc1);
#pragma unroll
    for (int i = 0; i < 4; ++i) {
        int nt = wave + 4 * i;
#pragma unroll
        for (int i2 = 0; i2 < 4; ++i2) {
            AhB[(g * 4 + i2) * BST + nt * 16 + r] = (_Float16)silu(acc0[i][i2]);
            AhB[(16 + g * 4 + i2) * BST + nt * 16 + r] = (_Float16)silu(acc1[i][i2]);
        }
    }
    __syncthreads();
    mfma_gemm2<16>(8, AhB, BST, W2bT, t, acc0, acc1);
#pragma unroll
    for (int i = 0; i < 4; ++i) {
        int nt = wave + 4 * i;
#pragma unroll
        for (int i2 = 0; i2 < 4; ++i2) {
            int ro = g * 4 + i2, col = nt * 16 + r;
            Ah[ro * AST + col] = (_Float16)(s_cut[ro] * silu(acc0[i][i2]));
            Ah[(16 + ro) * AST + col] = (_Float16)(s_cut[16 + ro] * silu(acc1[i][i2]));
        }
    }
    __syncthreads();
}

// lnorm(featN[center]) -> Ah cols 256..351 f16
__device__ __forceinline__ void gather_lnorm(const float* __restrict__ featN,
                                             const int* __restrict__ eidx,
                                             const int* __restrict__ eord,
                                             int e0, int t, _Float16* Ah) {
    for (int i = t; i < EB * 96; i += 256) {
        int ee = i / 96, rem = i - ee * 96;
        int l = rem >> 5, kk = rem & 31;
        int off = (l == 0) ? 0 : ((l == 1) ? 1 : 4);
        int d = (l == 0) ? 1 : ((l == 1) ? 3 : 5);
        int e = eord ? eord[e0 + ee] : (e0 + ee);
        const float* f = featN + (size_t)eidx[e] * 288 + kk;
        float s = 1e-8f;
        for (int mm = off; mm < off + d; ++mm) { float x = f[mm * 32]; s = fmaf(x, x, s); }
        Ah[ee * AST + 256 + rem] = (_Float16)sqrtf(s);
    }
}

// unsorted atomic scatter into env (fallback)
__device__ __forceinline__ void scatter_env(const float* __restrict__ edge_attr,
                                            const int* __restrict__ eidx,
                                            const float* s_w, const float* s_cut,
                                            int e0, int t, float* __restrict__ env) {
    for (int i = t; i < EB * 32; i += 256) {
        int el = i >> 5, k = i & 31;
        int e = e0 + el;
        float cw = s_cut[el];
        int n = eidx[e];
        float w0 = s_w[el * 96 + k * 3 + 0] * cw;
        float w1 = s_w[el * 96 + k * 3 + 1] * cw;
        float w2 = s_w[el * 96 + k * 3 + 2] * cw;
        float* dst = env + (size_t)n * 288 + k;
#pragma unroll
        for (int m = 0; m < 9; ++m) {
            float w = (m == 0) ? w0 : ((m < 4) ? w1 : w2);
            atomicAdd(dst + m * 32, edge_attr[(size_t)e * 9 + m] * w);
        }
    }
}

// sorted segmented-flush scatter: s_sh = sh*cut, s_nid nondecreasing
__device__ __forceinline__ void scatter_sorted(const float* s_sh, const int* s_nid,
                                               const float* s_w, int t,
                                               float* __restrict__ env) {
    for (int pp = t; pp < 288; pp += 256) {
        int m = pp >> 5, k = pp & 31;
        int l = (m == 0) ? 0 : ((m < 4) ? 1 : 2);
        float run = 0.f;
        int nprev = s_nid[0];
        for (int el = 0; el < EB; ++el) {
            int nid = s_nid[el];
            if (nid != nprev) {
                atomicAdd(&env[(size_t)nprev * 288 + m * 32 + k], run);
                run = 0.f;
                nprev = nid;
            }
            run = fmaf(s_sh[el * 9 + m], s_w[el * 96 + k * 3 + l], run);
        }
        atomicAdd(&env[(size_t)nprev * 288 + m * 32 + k], run);
    }
}

// NT=6 epilogue -> s_w (f32)
__device__ __forceinline__ void epi6_f32(const f32x4* acc0, const f32x4* acc1, int t,
                                         float* s_w) {
    int wave = t >> 6, lane = t & 63, r = lane & 15, g = lane >> 4;
#pragma unroll
    for (int i = 0; i < 2; ++i) {
        int nt = wave + 4 * i;
        if (nt < 6) {
#pragma unroll
            for (int i2 = 0; i2 < 4; ++i2) {
                s_w[(g * 4 + i2) * 96 + nt * 16 + r] = acc0[i][i2];
                s_w[(16 + g * 4 + i2) * 96 + nt * 16 + r] = acc1[i][i2];
            }
        }
    }
}

// ---------------------------------------------------------------- K1: lat0 -> persist lat0h + w0h + scatter round 0
__global__ __launch_bounds__(256) void k1_lat_scatter0(
    const float* __restrict__ nodeinv, const float* __restrict__ edgeinv,
    const float* __restrict__ elen, const float* __restrict__ edge_attr,
    const int* __restrict__ eidx, const _Float16* __restrict__ W2aT,
    const _Float16* __restrict__ W2bT, const _Float16* __restrict__ Wenv0T,
    float* __restrict__ env, _Float16* __restrict__ lat0h,
    _Float16* __restrict__ w0h, const int* __restrict__ eord) {
    __shared__ alignas(16) _Float16 Ah[EB * AST];
    __shared__ alignas(16) _Float16 AhB[EB * BST];
    __shared__ float s_cut[EB];
    __shared__ float s_sh[EB * 9];
    __shared__ int s_nid[EB];
    float* s_w = (float*)AhB;  // overlay: AhB dead after lat0
    int t = threadIdx.x;
    int e0 = blockIdx.x * EB;
    int wave = t >> 6, lane = t & 63, r = lane & 15, g = lane >> 4;
    gather_latin(nodeinv, edgeinv, elen, eidx, eord, e0, t, Ah, s_cut);
    __syncthreads();
    lat0_mfma2(W2aT, W2bT, t, Ah, AhB, s_cut);
    // persist lat0 (f16), p-indexed
    for (int i = t; i < EB * 32; i += 256) {
        int ee = i >> 5, c8 = (i & 31) * 8;
        *(f16x8*)(lat0h + (size_t)(e0 + ee) * 256 + c8) =
            *(const f16x8*)(Ah + ee * AST + c8);
    }
    // combined Wenv0 GEMM (12 n-tiles over 192 cols)
    f32x4 acc0[3], acc1[3];
    mfma_gemm2<12>(8, Ah, AST, Wenv0T, t, acc0, acc1);
#pragma unroll
    for (int i = 0; i < 3; ++i) {
        int nt = wave + 4 * i;
        if (nt < 6) {
#pragma unroll
            for (int i2 = 0; i2 < 4; ++i2) {
                w0h[(size_t)(e0 + g * 4 + i2) * 96 + nt * 16 + r] = (_Float16)acc0[i][i2];
                w0h[(size_t)(e0 + 16 + g * 4 + i2) * 96 + nt * 16 + r] = (_Float16)acc1[i][i2];
            }
        } else {
#pragma unroll
            for (int i2 = 0; i2 < 4; ++i2) {
                s_w[(g * 4 + i2) * 96 + (nt - 6) * 16 + r] = acc0[i][i2];
                s_w[(16 + g * 4 + i2) * 96 + (nt - 6) * 16 + r] = acc1[i][i2];
            }
        }
    }
    if (eord) {
        if (t < EB) s_nid[t] = eidx[eord[e0 + t]];
        for (int i = t; i < EB * 9; i += 256) {
            int el = i / 9, m = i - el * 9;
            s_sh[i] = edge_attr[(size_t)eord[e0 + el] * 9 + m] * s_cut[el];
        }
    }
    __syncthreads();
    if (eord) scatter_sorted(s_sh, s_nid, s_w, t, env);
    else      scatter_env(edge_attr, eidx, s_w, s_cut, e0, t, env);
}

// ---------------------------------------------------------------- node transform (env input)
__global__ __launch_bounds__(288) void k_node(
    const float* envin, const float* __restrict__ nodeinv,
    const float* __restrict__ Wenvlin, const float* __restrict__ Wprod,
    const float* __restrict__ Wfeat, float* featOut) {
    __shared__ float s_env[288];
    __shared__ float s_inv[64];
    __shared__ float s_mix[288];
    __shared__ float s_ew[96];
    int n = blockIdx.x;
    int t = threadIdx.x;
    s_env[t] = envin[(size_t)n * 288 + t] * (1.0f / 32.0f);
    if (t < 64) s_inv[t] = nodeinv[n * 64 + t];
    __syncthreads();
    int m = t >> 5, j = t & 31;
    int l = (m == 0) ? 0 : ((m < 4) ? 1 : 2);
    float a = 0.f;
    for (int k = 0; k < 32; ++k) a = fmaf(s_env[m * 32 + k], Wenvlin[l * 1024 + k * 32 + j], a);
    if (t < 96) {
        int c = t >> 5, jj = t & 31;
        float b = 0.f;
        for (int tt = 0; tt < 64; ++tt) b = fmaf(s_inv[tt], Wprod[c * 2048 + tt * 32 + jj], b);
        s_ew[t] = b;
    }
    s_mix[t] = a;
    __syncthreads();
    float s = s_mix[j];
    float p = s_mix[t] * (s_ew[j] + s_ew[32 + j] * s + s_ew[64 + j] * s * s);
    __syncthreads();
    s_env[t] = p;
    __syncthreads();
    float o = 0.f;
    for (int jl = 0; jl < 32; ++jl) o = fmaf(s_env[m * 32 + jl], Wfeat[l * 1024 + jl * 32 + j], o);
    featOut[(size_t)n * 288 + t] = o;
}

// ---------------------------------------------------------------- K3: load lat0h -> lat1 (overwrite) -> Wenv1 -> scatter
__global__ __launch_bounds__(256) void k3_update_scatter1(
    const float* __restrict__ elen, const float* __restrict__ edge_attr,
    const int* __restrict__ eidx, const _Float16* __restrict__ Wl1aT,
    const _Float16* __restrict__ Wl1bT, const _Float16* __restrict__ Wenv1T,
    const float* __restrict__ featN0, float* __restrict__ env,
    _Float16* __restrict__ lat01h, const int* __restrict__ eord) {
    __shared__ alignas(16) _Float16 Ah[EB * AST];
    __shared__ alignas(16) _Float16 AhB[EB * BST];
    __shared__ float s_cut[EB];
    __shared__ float s_sh[EB * 9];
    __shared__ int s_nid[EB];
    float* s_w = (float*)AhB;
    int t = threadIdx.x;
    int e0 = blockIdx.x * EB;
    int wave = t >> 6, lane = t & 63, r = lane & 15, g = lane >> 4;
    if (t < EB) {
        int e = eord ? eord[e0 + t] : (e0 + t);
        s_cut[t] = cutf(elen[e]);
    }
    for (int i = t; i < EB * 32; i += 256) {
        int ee = i >> 5, c8 = (i & 31) * 8;
        *(f16x8*)(Ah + ee * AST + c8) =
            *(const f16x8*)(lat01h + (size_t)(e0 + ee) * 256 + c8);
    }
    gather_lnorm(featN0, eidx, eord, e0, t, Ah);
    __syncthreads();
    f32x4 acc0[4], acc1[4];
    mfma_gemm2<16>(11, Ah, AST, Wl1aT, t, acc0, acc1);
#pragma unroll
    for (int i = 0; i < 4; ++i) {
        int nt = wave + 4 * i;
#pragma unroll
        for (int i2 = 0; i2 < 4; ++i2) {
            AhB[(g * 4 + i2) * BST + nt * 16 + r] = (_Float16)silu(acc0[i][i2]);
            AhB[(16 + g * 4 + i2) * BST + nt * 16 + r] = (_Float16)silu(acc1[i][i2]);
        }
    }
    __syncthreads();
    mfma_gemm2<16>(8, AhB, BST, Wl1bT, t, acc0, acc1);
#pragma unroll
    for (int i = 0; i < 4; ++i) {
        int nt = wave + 4 * i;
#pragma unroll
        for (int i2 = 0; i2 < 4; ++i2) {
            int ro = g * 4 + i2, col = nt * 16 + r;
            float v0 = 0.8944271909999159f * (float)Ah[ro * AST + col] +
                       0.4472135954999579f * s_cut[ro] * silu(acc0[i][i2]);
            _Float16 h0 = (_Float16)v0;
            Ah[ro * AST + col] = h0;
            lat01h[(size_t)(e0 + ro) * 256 + col] = h0;
            float v1 = 0.8944271909999159f * (float)Ah[(16 + ro) * AST + col] +
                       0.4472135954999579f * s_cut[16 + ro] * silu(acc1[i][i2]);
            _Float16 h1 = (_Float16)v1;
            Ah[(16 + ro) * AST + col] = h1;
            lat01h[(size_t)(e0 + 16 + ro) * 256 + col] = h1;
        }
    }
    __syncthreads();
    mfma_gemm2<6>(8, Ah, AST, Wenv1T, t, acc0, acc1);
    epi6_f32(acc0, acc1, t, s_w);
    if (eord) {
        if (t < EB) s_nid[t] = eidx[eord[e0 + t]];
        for (int i = t; i < EB * 9; i += 256) {
            int el = i / 9, m = i - el * 9;
            s_sh[i] = edge_attr[(size_t)eord[e0 + el] * 9 + m] * s_cut[el];
        }
    }
    __syncthreads();
    if (eord) scatter_sorted(s_sh, s_nid, s_w, t, env);
    else      scatter_env(edge_attr, eidx, s_w, s_cut, e0, t, env);
}

// ---------------------------------------------------------------- K5 fast v11: per-l accumulator (reg diet), single-buffer staging
#define FEB 128
__global__ __launch_bounds__(256) void k5_fast(
    const float* __restrict__ edge_attr, const int* __restrict__ eidx,
    const _Float16* __restrict__ lat1h, const _Float16* __restrict__ w0h,
    const _Float16* __restrict__ Bfin3, const _Float16* __restrict__ Wro1T32,
    const float* __restrict__ Wro2, const float* __restrict__ featN1,
    const int* __restrict__ eord, float* __restrict__ out) {
    __shared__ alignas(16) _Float16 Bst[8192];      // 16 KB single stage buffer
    __shared__ alignas(16) _Float16 s_S[FEB * SST]; // 24.5 KB: S, then scal overlay
    int t = threadIdx.x;
    int e0 = blockIdx.x * FEB;
    int wave = t >> 6, lane = t & 63;
    int r31 = lane & 31, kh5 = lane >> 5;
    // ---- S gather
    for (int i = t; i < FEB * 96; i += 256) {
        int ee = i / 96, rem = i - ee * 96;
        int l = rem >> 5, kk = rem & 31;
        int off = (l == 0) ? 0 : ((l == 1) ? 1 : 4);
        int d = (l == 0) ? 1 : ((l == 1) ? 3 : 5);
        int e = eord ? eord[e0 + ee] : (e0 + ee);
        const float* f = featN1 + (size_t)eidx[e] * 288 + kk;
        float s = 0.f;
        for (int mm = off; mm < off + d; ++mm)
            s = fmaf(f[mm * 32], edge_attr[(size_t)e * 9 + mm], s);
        s_S[ee * SST + rem] = (_Float16)s;
    }
    // ---- lat1 frags (used as MFMA *B* in contraction, *A* in readout)
    f16x8 a2[16];
#pragma unroll
    for (int q = 0; q < 16; ++q)
        a2[q] = *(const f16x8*)(lat1h + (size_t)(e0 + wave * 32 + r31) * 256 +
                                q * 16 + kh5 * 8);
    // ---- prologue: stage 0, chunk-strided (lane-contiguous)
#pragma unroll
    for (int c = 0; c < 4; ++c) {
        f16x8 gc = *(const f16x8*)(Bfin3 + (size_t)(c * 256 + t) * 8);
        *(f16x8*)&Bst[(c * 256 + t) * 8] = gc;
    }
    __syncthreads();
    const f32x16 z16 = {0.f, 0.f, 0.f, 0.f, 0.f, 0.f, 0.f, 0.f,
                        0.f, 0.f, 0.f, 0.f, 0.f, 0.f, 0.f, 0.f};
    int pe = e0 + wave * 32 + r31;  // this lane's edge (p-space)
#pragma unroll 1
    for (int l = 0; l < 3; ++l) {
        f32x16 accl = z16;          // single live accumulator per l (reg diet)
#pragma unroll 1
        for (int ke = 0; ke < 32; ++ke) {
            int s = l * 32 + ke;
            f16x8 g0, g1, g2, g3;
            if (s < 95) {  // issue next-stage loads early
                const _Float16* g = Bfin3 + (size_t)(s + 1) * 8192;
                g0 = *(const f16x8*)(g + (size_t)(0 * 256 + t) * 8);
                g1 = *(const f16x8*)(g + (size_t)(1 * 256 + t) * 8);
                g2 = *(const f16x8*)(g + (size_t)(2 * 256 + t) * 8);
                g3 = *(const f16x8*)(g + (size_t)(3 * 256 + t) * 8);
            }
            float sf = (float)s_S[(wave * 32 + r31) * SST + l * 32 + ke];
            f32x16 ac = z16;
#pragma unroll
            for (int q = 0; q < 16; ++q) {
                f16x8 bf = *(const f16x8*)&Bst[q * 512 + lane * 8];
                // D^T: A = Wfin frag (rows=j), B = lat1 (cols=e)
                ac = __builtin_amdgcn_mfma_f32_32x32x16_f16(bf, a2[q], ac, 0, 0, 0);
            }
#pragma unroll
            for (int reg = 0; reg < 16; ++reg)
                accl[reg] = fmaf(sf, ac[reg], accl[reg]);  // deferred S (f32)
            __syncthreads();  // all reads of Bst done
            if (s < 95) {
                *(f16x8*)&Bst[(0 * 256 + t) * 8] = g0;
                *(f16x8*)&Bst[(1 * 256 + t) * 8] = g1;
                *(f16x8*)&Bst[(2 * 256 + t) * 8] = g2;
                *(f16x8*)&Bst[(3 * 256 + t) * 8] = g3;
            }
            __syncthreads();  // next stage visible
        }
        // ---- apply w0 for this l immediately (s_S rows are wave-private;
        //      scal positions == this l's now-dead S values)
#pragma unroll
        for (int reg = 0; reg < 16; ++reg) {
            int jrow = (reg & 3) + 8 * (reg >> 2) + 4 * kh5;  // 32x32 D layout (m74/m101)
            float w0 = (float)w0h[(size_t)pe * 96 + jrow * 3 + l];
            s_S[(wave * 32 + r31) * SST + l * 32 + jrow] = (_Float16)(accl[reg] * w0);
        }
    }
    __syncthreads();
    // ---- readout: 32x32 tiles, rows = edges (a2 as A), 8 col-blocks
    float v16[16];
#pragma unroll
    for (int reg = 0; reg < 16; ++reg) v16[reg] = 0.f;
#pragma unroll 1
    for (int cb = 0; cb < 8; ++cb) {
        f32x16 racc = z16;
#pragma unroll
        for (int ks2 = 0; ks2 < 22; ++ks2) {
            f16x8 af = (ks2 < 16)
                ? a2[ks2]
                : *(const f16x8*)&s_S[(wave * 32 + r31) * SST + (ks2 - 16) * 16 + kh5 * 8];
            f16x8 b = *(const f16x8*)(Wro1T32 + ((size_t)(cb * 22 + ks2) * 512 + lane * 8));
            racc = __builtin_amdgcn_mfma_f32_32x32x16_f16(af, b, racc, 0, 0, 0);
        }
        float w2 = Wro2[cb * 32 + r31];
#pragma unroll
        for (int reg = 0; reg < 16; ++reg) v16[reg] += silu(racc[reg]) * w2;
    }
#pragma unroll
    for (int off = 1; off < 32; off <<= 1)
#pragma unroll
        for (int reg = 0; reg < 16; ++reg) v16[reg] += __shfl_xor(v16[reg], off);
    if (r31 == 0) {
#pragma unroll
        for (int reg = 0; reg < 16; ++reg) {
            int row = (reg & 3) + 8 * (reg >> 2) + 4 * kh5;
            int pidx = e0 + wave * 32 + row;
            int e = eord ? eord[pidx] : pidx;
            out[e] = v16[reg];
        }
    }
}

// ----------------------------------------------------------------
extern "C" void kernel_launch(void* const* d_in, const int* in_sizes, int n_in,
                              void* d_out, int out_size, void* d_ws, size_t ws_size,
                              hipStream_t stream) {
    (void)in_sizes; (void)n_in; (void)out_size;
    const float* edge_attr = (const float*)d_in[0];
    const float* edge_len  = (const float*)d_in[1];
    const float* edge_inv  = (const float*)d_in[2];
    const float* node_inv  = (const float*)d_in[3];
    const float* W2a     = (const float*)d_in[4];
    const float* W2b     = (const float*)d_in[5];
    const float* Wl1a    = (const float*)d_in[6];
    const float* Wl1b    = (const float*)d_in[7];
    const float* Wenv0   = (const float*)d_in[8];
    const float* Wenv1   = (const float*)d_in[9];
    const float* Wenvlin = (const float*)d_in[10];
    const float* Wprod   = (const float*)d_in[11];
    const float* Wfeat   = (const float*)d_in[12];
    const float* Wfinlat = (const float*)d_in[13];
    const float* Wro1    = (const float*)d_in[14];
    const float* Wro2    = (const float*)d_in[15];
    const int* eidx      = (const int*)d_in[16];
    float* out = (float*)d_out;

    _Float16* p = (_Float16*)d_ws;
    _Float16* Bfin3   = p; p += 786432;
    _Float16* W2aT    = p; p += 40960;
    _Float16* W2bT    = p; p += 65536;
    _Float16* Wenv0T  = p; p += 49152;   // NT=12 combined (cols 0..191)
    _Float16* Wenv1T  = p; p += 24576;
    _Float16* Wl1aT   = p; p += 90112;
    _Float16* Wl1bT   = p; p += 65536;
    _Float16* Wro1T32 = p; p += 90112;
    float* env    = (float*)p;
    float* featN0 = env + (size_t)NNODES * 288;
    char* after = (char*)(featN0 + (size_t)NNODES * 288);
    size_t need_base = (size_t)(after - (char*)d_ws);
    if (ws_size < need_base) return;
    _Float16* lat01h = (_Float16*)after;                      // NE*256 f16 (lat0 then lat1)
    _Float16* w0h    = lat01h + (size_t)NE * 256;             // NE*96 f16
    size_t need = need_base + (size_t)NE * (256 + 96) * sizeof(_Float16);
    if (ws_size < need) return;  // proven to fit since R7
    int* eord   = (int*)((char*)d_ws + need);                 // NE ints
    int* seg    = eord + NE;                                  // NNODES+1
    int* cursor = seg + NNODES + 1;                           // NNODES
    size_t need_sorted = need + (size_t)(NE + 2 * NNODES + 1) * sizeof(int);
    bool sorted = (ws_size >= need_sorted);
    const int* eordk = sorted ? eord : nullptr;

    const int ENV_N = NNODES * 288;
    k_packfin3<<<3072, 256, 0, stream>>>(Wfinlat, Bfin3);
    k_packf<<<160, 256, 0, stream>>>(W2a, W2aT, 136, 5, 16, 256, 0);
    k_packf<<<256, 256, 0, stream>>>(W2b, W2bT, 256, 8, 16, 256, 0);
    k_packf<<<192, 256, 0, stream>>>(Wenv0, Wenv0T, 256, 8, 12, 192, 0);
    k_packf<<<96, 256, 0, stream>>>(Wenv1, Wenv1T, 256, 8, 6, 96, 0);
    k_packf<<<352, 256, 0, stream>>>(Wl1a, Wl1aT, 352, 11, 16, 256, 0);
    k_packf<<<256, 256, 0, stream>>>(Wl1b, Wl1bT, 256, 8, 16, 256, 0);
    k_packro5<<<352, 256, 0, stream>>>(Wro1, Wro1T32);

    if (sorted) {
        k_zero<<<(NNODES + 255) / 256, 256, 0, stream>>>((float*)cursor, NNODES);
        k_hist<<<NE / 256, 256, 0, stream>>>(eidx, cursor);   // cursor = counts
        k_scan<<<1, 256, 0, stream>>>(cursor, seg, cursor);   // seg + cursor (aliased, fixed)
        k_place<<<NE / 256, 256, 0, stream>>>(eidx, cursor, eord);
    }

    k_zero<<<(ENV_N + 255) / 256, 256, 0, stream>>>(env, ENV_N);
    k1_lat_scatter0<<<NBLK, 256, 0, stream>>>(node_inv, edge_inv, edge_len, edge_attr,
                                              eidx, W2aT, W2bT, Wenv0T, env, lat01h, w0h,
                                              eordk);
    k_node<<<NNODES, 288, 0, stream>>>(env, node_inv, Wenvlin, Wprod, Wfeat, featN0);
    k_zero<<<(ENV_N + 255) / 256, 256, 0, stream>>>(env, ENV_N);
    k3_update_scatter1<<<NBLK, 256, 0, stream>>>(edge_len, edge_attr, eidx,
                                                 Wl1aT, Wl1bT, Wenv1T, featN0, env, lat01h,
                                                 eordk);
    k_node<<<NNODES, 288, 0, stream>>>(env, node_inv, Wenvlin + 3072, Wprod + 6144,
                                       Wfeat + 3072, env);  // in-place: env1 -> featN1
    k5_fast<<<NE / FEB, 256, 0, stream>>>(edge_attr, eidx, lat01h, w0h, Bfin3, Wro1T32,
                                          Wro2, env, eordk, out);
}